// Round 17
// baseline (172.246 us; speedup 1.0000x reference)
//
#include <hip/hip_runtime.h>

#define NN 100000
#define NE 1600000
#define NT64 1563    // ceil(NN / 64)

#define BSH 7
#define BNODES 128               // nodes per bucket
#define NBUCK 782                // ceil(NN / 128)
#define NBUCKP 784
#define CAP 2560                 // words per bucket region (exp 2048, +11 sigma)
#define ECH 8192                 // edges per chunk
#define NCHK 196                 // ceil(NE / ECH)
#define WFRAG_BLKS 272           // 139264 / 512

typedef _Float16 half8v __attribute__((ext_vector_type(8)));
typedef _Float16 half4v __attribute__((ext_vector_type(4)));
typedef float f32x4 __attribute__((ext_vector_type(4)));

// ---------------- W -> fp16 B-fragment layout ----------------
// Wf[((kt*(N/16)+nt)*64 + l)*8 + j] = W[(kt*32 + (l>>4)*8 + j)*N + nt*16 + (l&15)]

__device__ __forceinline__ void wfrag_one(const float* __restrict__ W,
                                          _Float16* __restrict__ Wf, int idx, int N) {
    int j = idx & 7;
    int l = (idx >> 3) & 63;
    int f = idx >> 9;
    int nt = f % (N / 16);
    int kt = f / (N / 16);
    int k = kt * 32 + (l >> 4) * 8 + j;
    int c = nt * 16 + (l & 15);
    Wf[idx] = (_Float16)W[k * N + c];
}

// ---------------- merged: bucket count (blocks 0..195) | wfrag (196..467) ----------------

__global__ __launch_bounds__(512) void k_count_wfrag(const int* __restrict__ dst,
                                                     int* __restrict__ histT,
                                                     const float* __restrict__ W1,
                                                     const float* __restrict__ W2,
                                                     const float* __restrict__ W3,
                                                     _Float16* __restrict__ Wf1,
                                                     _Float16* __restrict__ Wf2,
                                                     _Float16* __restrict__ Wf3) {
    const int t = threadIdx.x;
    if (blockIdx.x >= NCHK) {
        int idx = (blockIdx.x - NCHK) * 512 + t;
        if (idx < 65536) wfrag_one(W1, Wf1, idx, 256);
        else if (idx < 131072) wfrag_one(W2, Wf2, idx - 65536, 256);
        else if (idx < 139264) wfrag_one(W3, Wf3, idx - 131072, 32);
        return;
    }
    __shared__ int h[NBUCKP];
    const int blk = blockIdx.x;
    for (int b = t; b < NBUCKP; b += 512) h[b] = 0;
    __syncthreads();
    const int ebase = blk * ECH + t * 16;
#pragma unroll
    for (int q = 0; q < 4; q++) {
        int e = ebase + q * 4;
        if (e + 4 <= NE) {
            int4 d4 = *reinterpret_cast<const int4*>(dst + e);
            atomicAdd(&h[d4.x >> BSH], 1);
            atomicAdd(&h[d4.y >> BSH], 1);
            atomicAdd(&h[d4.z >> BSH], 1);
            atomicAdd(&h[d4.w >> BSH], 1);
        } else {
            for (int p = e; p < NE; p++) atomicAdd(&h[dst[p] >> BSH], 1);
            break;
        }
    }
    __syncthreads();
    for (int b = t; b < NBUCK; b += 512) histT[(long long)b * NCHK + blk] = h[b];
}

// ---------------- per-bucket exclusive scan over chunks ----------------

__global__ __launch_bounds__(256) void k_scanb(int* __restrict__ histT,
                                               int* __restrict__ cntb) {
    __shared__ int s[256];
    const int b = blockIdx.x, t = threadIdx.x;
    int* row = histT + (long long)b * NCHK;
    int v = (t < NCHK) ? row[t] : 0;
    s[t] = v;
    __syncthreads();
    for (int off = 1; off < 256; off <<= 1) {
        int u = (t >= off) ? s[t - off] : 0;
        __syncthreads();
        s[t] += u;
        __syncthreads();
    }
    if (t < NCHK) row[t] = s[t] - v;
    if (t == 255) cntb[b] = s[255];
}

// ---------------- bucket partition scatter (standalone) ----------------

__global__ __launch_bounds__(512) void k_part(const int* __restrict__ src,
                                              const int* __restrict__ dst,
                                              const int* __restrict__ histT,
                                              int* __restrict__ data) {
    __shared__ int curs[NBUCKP];
    const int t = threadIdx.x, blk = blockIdx.x;
    for (int b = t; b < NBUCKP; b += 512)
        curs[b] = b * CAP + ((b < NBUCK) ? histT[(long long)b * NCHK + blk] : 0);
    __syncthreads();
    const int ebase = blk * ECH + t * 16;
#pragma unroll
    for (int q = 0; q < 4; q++) {
        int e = ebase + q * 4;
        if (e + 4 <= NE) {
            int4 d4 = *reinterpret_cast<const int4*>(dst + e);
            int4 s4 = *reinterpret_cast<const int4*>(src + e);
            int p0 = atomicAdd(&curs[d4.x >> BSH], 1);
            data[p0] = (s4.x << BSH) | (d4.x & (BNODES - 1));
            int p1 = atomicAdd(&curs[d4.y >> BSH], 1);
            data[p1] = (s4.y << BSH) | (d4.y & (BNODES - 1));
            int p2 = atomicAdd(&curs[d4.z >> BSH], 1);
            data[p2] = (s4.z << BSH) | (d4.z & (BNODES - 1));
            int p3 = atomicAdd(&curs[d4.w >> BSH], 1);
            data[p3] = (s4.w << BSH) | (d4.w & (BNODES - 1));
        } else {
            for (int p = e; p < NE; p++) {
                int d = dst[p], sv = src[p];
                int pos = atomicAdd(&curs[d >> BSH], 1);
                data[pos] = (sv << BSH) | (d & (BNODES - 1));
            }
            break;
        }
    }
}

// ---------------- Layer 1: x -> h1 (raw swizzled 32KB tile images), 64 rows/block ----------------
// 8 waves; wave w owns cols [32w,+32): each W-fragment load feeds 4 MFMAs.

__global__ __launch_bounds__(512) void k_lay1(const float* __restrict__ x,
                                              const _Float16* __restrict__ Wf1,
                                              const float* __restrict__ b1,
                                              _Float16* __restrict__ h1g) {
    __shared__ char buf[64 * 512];  // 32 KB
    const int t = threadIdx.x;
    const int lane = t & 63;
    const int G = lane >> 4;
    const int w = t >> 6;
    const int T = blockIdx.x;
    const long long row0 = (long long)T * 64;

    const half8v* W1f = reinterpret_cast<const half8v*>(Wf1);
    float bvs[2];
#pragma unroll
    for (int n2 = 0; n2 < 2; n2++) bvs[n2] = b1[w * 32 + n2 * 16 + (lane & 15)];

    // stage x tile fp32 -> fp16 swizzled (coalesced float4), zero-pad past NN
    {
        const float4* A4 = reinterpret_cast<const float4*>(x + row0 * 256);
#pragma unroll
        for (int i = t; i < 4096; i += 512) {
            int r = i >> 6, c4 = i & 63;
            float4 v = make_float4(0.f, 0.f, 0.f, 0.f);
            if (row0 + r < NN) v = A4[i];
            half4v hv;
            hv[0] = (_Float16)v.x; hv[1] = (_Float16)v.y;
            hv[2] = (_Float16)v.z; hv[3] = (_Float16)v.w;
            int bo = (r * 512 + c4 * 8) ^ ((r & 7) << 4);
            *reinterpret_cast<half4v*>(buf + bo) = hv;
        }
    }
    __syncthreads();

    f32x4 acc[4][2];
#pragma unroll
    for (int mt = 0; mt < 4; mt++)
#pragma unroll
        for (int n2 = 0; n2 < 2; n2++) acc[mt][n2] = (f32x4)0.f;
#pragma unroll
    for (int kt = 0; kt < 8; kt++) {
        half8v a[4], bfr[2];
#pragma unroll
        for (int n2 = 0; n2 < 2; n2++)
            bfr[n2] = W1f[(kt * 16 + 2 * w + n2) * 64 + lane];
#pragma unroll
        for (int mt = 0; mt < 4; mt++) {
            int row = mt * 16 + (lane & 15);
            int bo = (row * 512 + kt * 64 + (G << 4)) ^ ((row & 7) << 4);
            a[mt] = *reinterpret_cast<const half8v*>(buf + bo);
        }
#pragma unroll
        for (int mt = 0; mt < 4; mt++)
#pragma unroll
            for (int n2 = 0; n2 < 2; n2++)
                acc[mt][n2] = __builtin_amdgcn_mfma_f32_16x16x32_f16(a[mt], bfr[n2], acc[mt][n2], 0, 0, 0);
    }
    __syncthreads();

    // bias+relu -> fp16 back into LDS (swizzled image)
#pragma unroll
    for (int mt = 0; mt < 4; mt++)
#pragma unroll
        for (int n2 = 0; n2 < 2; n2++) {
            int colc = w * 32 + n2 * 16 + (lane & 15);
            float bb = bvs[n2];
#pragma unroll
            for (int r = 0; r < 4; r++) {
                int row = mt * 16 + G * 4 + r;
                float v = fmaxf(acc[mt][n2][r] + bb, 0.f);
                int bo = (row * 512 + colc * 2) ^ ((row & 7) << 4);
                *reinterpret_cast<_Float16*>(buf + bo) = (_Float16)v;
            }
        }
    __syncthreads();

    // dump raw image -> global (pure 16B memcpy)
    {
        half8v* dstp = reinterpret_cast<half8v*>(h1g + (size_t)T * 16384);
        const half8v* srcp = reinterpret_cast<const half8v*>(buf);
#pragma unroll
        for (int i = t; i < 2048; i += 512) dstp[i] = srcp[i];
    }
}

// ---------------- per-bucket LDS counting sort -> CSR + dinv ----------------
// Own launch: k_lay23 reads dinv (R15 race lesson).

__global__ __launch_bounds__(256) void k_sortb(const int* __restrict__ data,
                                               const int* __restrict__ cntb,
                                               int* __restrict__ col,
                                               int* __restrict__ begp,
                                               int* __restrict__ endp,
                                               float* __restrict__ dinv) {
    __shared__ int hist[BNODES];
    __shared__ int scn[BNODES];
    __shared__ int curs[BNODES];
    const int b = blockIdx.x, t = threadIdx.x;
    if (t < BNODES) hist[t] = 0;
    __syncthreads();
    const int cnt = cntb[b];
    const int* wp = data + b * CAP;
    for (int e = t; e < cnt; e += 256) atomicAdd(&hist[wp[e] & (BNODES - 1)], 1);
    __syncthreads();
    if (t < BNODES) scn[t] = hist[t];
    __syncthreads();
    for (int off = 1; off < BNODES; off <<= 1) {
        int v = (t < BNODES && t >= off) ? scn[t - off] : 0;
        __syncthreads();
        if (t < BNODES) scn[t] += v;
        __syncthreads();
    }
    if (t < BNODES) {
        int beg = scn[t] - hist[t];
        curs[t] = beg;
        int node = (b << BSH) + t;
        if (node < NN) {
            begp[node] = b * CAP + beg;
            endp[node] = b * CAP + scn[t];
            dinv[node] = rsqrtf((float)(hist[t] + 1));
        }
    }
    __syncthreads();
    for (int e = t; e < cnt; e += 256) {
        int w = wp[e];
        int p = atomicAdd(&curs[w & (BNODES - 1)], 1);
        col[b * CAP + p] = w >> BSH;
    }
}

// ---------------- Layers 2+3: h1 image -> h0f (f16), hs0 (f16), 64 rows/block ----------------

__global__ __launch_bounds__(512) void k_lay23(const _Float16* __restrict__ h1g,
                                               const _Float16* __restrict__ Wf2,
                                               const _Float16* __restrict__ Wf3,
                                               const float* __restrict__ b2,
                                               const float* __restrict__ b3,
                                               const float* __restrict__ dinv,
                                               _Float16* __restrict__ h0f,
                                               _Float16* __restrict__ hs0) {
    __shared__ char buf[64 * 512];  // 32 KB
    const int t = threadIdx.x;
    const int lane = t & 63;
    const int G = lane >> 4;
    const int w = t >> 6;
    const int T = blockIdx.x;
    const long long row0 = (long long)T * 64;

    const half8v* W2f = reinterpret_cast<const half8v*>(Wf2);
    float bvs[2];
#pragma unroll
    for (int n2 = 0; n2 < 2; n2++) bvs[n2] = b2[w * 32 + n2 * 16 + (lane & 15)];

    // stage h1 image (pure 16B memcpy)
    {
        const half8v* srcp = reinterpret_cast<const half8v*>(h1g + (size_t)T * 16384);
        half8v* dstp = reinterpret_cast<half8v*>(buf);
#pragma unroll
        for (int i = t; i < 2048; i += 512) dstp[i] = srcp[i];
    }
    __syncthreads();

    // GEMM2
    f32x4 acc[4][2];
#pragma unroll
    for (int mt = 0; mt < 4; mt++)
#pragma unroll
        for (int n2 = 0; n2 < 2; n2++) acc[mt][n2] = (f32x4)0.f;
#pragma unroll
    for (int kt = 0; kt < 8; kt++) {
        half8v a[4], bfr[2];
#pragma unroll
        for (int n2 = 0; n2 < 2; n2++)
            bfr[n2] = W2f[(kt * 16 + 2 * w + n2) * 64 + lane];
#pragma unroll
        for (int mt = 0; mt < 4; mt++) {
            int row = mt * 16 + (lane & 15);
            int bo = (row * 512 + kt * 64 + (G << 4)) ^ ((row & 7) << 4);
            a[mt] = *reinterpret_cast<const half8v*>(buf + bo);
        }
#pragma unroll
        for (int mt = 0; mt < 4; mt++)
#pragma unroll
            for (int n2 = 0; n2 < 2; n2++)
                acc[mt][n2] = __builtin_amdgcn_mfma_f32_16x16x32_f16(a[mt], bfr[n2], acc[mt][n2], 0, 0, 0);
    }
    __syncthreads();

    // h2 -> LDS (swizzled fp16)
#pragma unroll
    for (int mt = 0; mt < 4; mt++)
#pragma unroll
        for (int n2 = 0; n2 < 2; n2++) {
            int colc = w * 32 + n2 * 16 + (lane & 15);
            float bb = bvs[n2];
#pragma unroll
            for (int r = 0; r < 4; r++) {
                int row = mt * 16 + G * 4 + r;
                float v = fmaxf(acc[mt][n2][r] + bb, 0.f);
                int bo = (row * 512 + colc * 2) ^ ((row & 7) << 4);
                *reinterpret_cast<_Float16*>(buf + bo) = (_Float16)v;
            }
        }
    __syncthreads();

    // GEMM3: 64 rows x 32 cols = 8 tiles, one per wave: mt3 = w>>1, ct3 = w&1
    {
        const half8v* W3f = reinterpret_cast<const half8v*>(Wf3);
        const int mt3 = w >> 1, ct3 = w & 1;
        const float bb3 = b3[ct3 * 16 + (lane & 15)];
        f32x4 a3 = (f32x4)0.f;
#pragma unroll
        for (int kt = 0; kt < 8; kt++) {
            int row = mt3 * 16 + (lane & 15);
            int bo = (row * 512 + kt * 64 + (G << 4)) ^ ((row & 7) << 4);
            half8v a = *reinterpret_cast<const half8v*>(buf + bo);
            half8v b = W3f[(kt * 2 + ct3) * 64 + lane];
            a3 = __builtin_amdgcn_mfma_f32_16x16x32_f16(a, b, a3, 0, 0, 0);
        }
        int colc = ct3 * 16 + (lane & 15);
#pragma unroll
        for (int r = 0; r < 4; r++) {
            long long row = row0 + mt3 * 16 + G * 4 + r;
            if (row < NN) {
                float v = a3[r] + bb3;
                h0f[row * 32 + colc] = (_Float16)v;
                hs0[row * 32 + colc] = (_Float16)(dinv[row] * v);
            }
        }
    }
}

// ---------------- fused APPNP step: one wave per node, 16 edges in flight ----------------

template<bool FINAL>
__global__ __launch_bounds__(256) void k_appnp(const int* __restrict__ begp,
                                               const int* __restrict__ endp,
                                               const int* __restrict__ col,
                                               const float* __restrict__ dinv,
                                               const _Float16* __restrict__ hs,
                                               const _Float16* __restrict__ h0f,
                                               void* __restrict__ outp) {
    int node = blockIdx.x * 4 + (threadIdx.x >> 6);
    if (node >= NN) return;
    const int lane = threadIdx.x & 63;
    const int slot = lane >> 2;
    const int cg = lane & 3;

    const int beg = begp[node];
    const int end = endp[node];
    const float dd = dinv[node];
    const half8v selfv = *reinterpret_cast<const half8v*>(hs + (size_t)node * 32 + cg * 8);
    const half8v h0v = *reinterpret_cast<const half8v*>(h0f + (size_t)node * 32 + cg * 8);

    float acc[8];
#pragma unroll
    for (int j = 0; j < 8; j++) acc[j] = 0.f;

    for (int e = beg + slot; e < end; e += 16) {
        int s = col[e];
        half8v v = *reinterpret_cast<const half8v*>(hs + (size_t)s * 32 + cg * 8);
#pragma unroll
        for (int j = 0; j < 8; j++) acc[j] += (float)v[j];
    }

#pragma unroll
    for (int off = 4; off < 64; off <<= 1) {
#pragma unroll
        for (int j = 0; j < 8; j++) acc[j] += __shfl_xor(acc[j], off, 64);
    }

    if (slot == 0) {
        float o[8];
#pragma unroll
        for (int j = 0; j < 8; j++)
            o[j] = 0.9f * dd * (acc[j] + (float)selfv[j]) + 0.1f * (float)h0v[j];
        size_t off = (size_t)node * 32 + cg * 8;
        if (FINAL) {
            float4 v0 = make_float4(o[0], o[1], o[2], o[3]);
            float4 v1 = make_float4(o[4], o[5], o[6], o[7]);
            float4* op = reinterpret_cast<float4*>((float*)outp + off);
            op[0] = v0; op[1] = v1;
        } else {
            half8v hv;
#pragma unroll
            for (int j = 0; j < 8; j++) hv[j] = (_Float16)(dd * o[j]);
            *reinterpret_cast<half8v*>((_Float16*)outp + off) = hv;
        }
    }
}

// ---------------- launch ----------------

extern "C" void kernel_launch(void* const* d_in, const int* in_sizes, int n_in,
                              void* d_out, int out_size, void* d_ws, size_t ws_size,
                              hipStream_t stream) {
    const float* x     = (const float*)d_in[0];
    const int*   ei    = (const int*)d_in[1];
    const float* W_in  = (const float*)d_in[2];
    const float* b_in  = (const float*)d_in[3];
    const float* W_h   = (const float*)d_in[4];
    const float* b_h   = (const float*)d_in[5];
    const float* W_out = (const float*)d_in[6];
    const float* b_out = (const float*)d_in[7];
    float* out = (float*)d_out;

    const int* srcv = ei;
    const int* dstv = ei + NE;

    char* ws = (char*)d_ws;
    _Float16* h0f  = (_Float16*)ws;                              // NN*32 f16
    _Float16* hs0  = h0f + (size_t)NN * 32;                      // NN*32 f16
    _Float16* hs1  = hs0 + (size_t)NN * 32;                      // NN*32 f16
    float* dinv    = (float*)(hs1 + (size_t)NN * 32);            // NN
    _Float16* Wf_in  = (_Float16*)(dinv + NN);                   // 256*256
    _Float16* Wf_h   = Wf_in + 256 * 256;                        // 256*256
    _Float16* Wf_out = Wf_h + 256 * 256;                         // 256*32
    _Float16* h1g    = Wf_out + 256 * 32;                        // NT64*16384 f16 (tile images)
    int* histT = (int*)(h1g + (size_t)NT64 * 16384);             // NBUCK*NCHK
    int* cntb  = histT + (size_t)NBUCK * NCHK;                   // NBUCKP
    int* data  = cntb + NBUCKP;                                  // NBUCKP*CAP
    int* col   = data + (size_t)NBUCKP * CAP;                    // NBUCKP*CAP
    int* begp  = col + (size_t)NBUCKP * CAP;                     // NN
    int* endp  = begp + NN;                                      // NN

    // --- [bucket count | W fragments] ---
    k_count_wfrag<<<NCHK + WFRAG_BLKS, 512, 0, stream>>>(dstv, histT,
                                                         W_in, W_h, W_out,
                                                         Wf_in, Wf_h, Wf_out);
    // --- per-bucket scan ---
    k_scanb<<<NBUCK, 256, 0, stream>>>(histT, cntb);

    // --- part scatter (standalone for diagnosis) ---
    k_part<<<NCHK, 512, 0, stream>>>(srcv, dstv, histT, data);

    // --- layer 1 (64-row tiles) ---
    k_lay1<<<NT64, 512, 0, stream>>>(x, Wf_in, b_in, h1g);

    // --- per-bucket counting sort -> CSR + dinv ---
    k_sortb<<<NBUCK, 256, 0, stream>>>(data, cntb, col, begp, endp, dinv);

    // --- layers 2+3 (64-row tiles) ---
    k_lay23<<<NT64, 512, 0, stream>>>(h1g, Wf_h, Wf_out, b_h, b_out, dinv, h0f, hs0);

    // --- APPNP: K = 2 (wave-per-node, 16-wide gather) ---
    k_appnp<false><<<(NN + 3) / 4, 256, 0, stream>>>(begp, endp, col, dinv, hs0, h0f, hs1);
    k_appnp<true ><<<(NN + 3) / 4, 256, 0, stream>>>(begp, endp, col, dinv, hs1, h0f, out);
}

// Round 18
// 170.942 us; speedup vs baseline: 1.0076x; 1.0076x over previous
//
#include <hip/hip_runtime.h>

#define NN 100000
#define NE 1600000
#define NT64 1563    // ceil(NN / 64)

#define BSH 7
#define BNODES 128               // nodes per bucket
#define NBUCK 782                // ceil(NN / 128)
#define NBUCKP 784
#define CAP 2560                 // words per bucket region (exp 2048, +11 sigma)
#define ECH 8192                 // edges per chunk
#define NCHK 196                 // ceil(NE / ECH)
#define WFRAG_BLKS 272           // 139264 / 512

typedef _Float16 half8v __attribute__((ext_vector_type(8)));
typedef _Float16 half4v __attribute__((ext_vector_type(4)));
typedef float f32x4 __attribute__((ext_vector_type(4)));

// ---------------- W -> fp16 B-fragment layout ----------------
// Wf[((kt*(N/16)+nt)*64 + l)*8 + j] = W[(kt*32 + (l>>4)*8 + j)*N + nt*16 + (l&15)]

__device__ __forceinline__ void wfrag_one(const float* __restrict__ W,
                                          _Float16* __restrict__ Wf, int idx, int N) {
    int j = idx & 7;
    int l = (idx >> 3) & 63;
    int f = idx >> 9;
    int nt = f % (N / 16);
    int kt = f / (N / 16);
    int k = kt * 32 + (l >> 4) * 8 + j;
    int c = nt * 16 + (l & 15);
    Wf[idx] = (_Float16)W[k * N + c];
}

// ---------------- merged: bucket count (blocks 0..195) | wfrag (196..467) ----------------

__global__ __launch_bounds__(512) void k_count_wfrag(const int* __restrict__ dst,
                                                     int* __restrict__ histT,
                                                     const float* __restrict__ W1,
                                                     const float* __restrict__ W2,
                                                     const float* __restrict__ W3,
                                                     _Float16* __restrict__ Wf1,
                                                     _Float16* __restrict__ Wf2,
                                                     _Float16* __restrict__ Wf3) {
    const int t = threadIdx.x;
    if (blockIdx.x >= NCHK) {
        int idx = (blockIdx.x - NCHK) * 512 + t;
        if (idx < 65536) wfrag_one(W1, Wf1, idx, 256);
        else if (idx < 131072) wfrag_one(W2, Wf2, idx - 65536, 256);
        else if (idx < 139264) wfrag_one(W3, Wf3, idx - 131072, 32);
        return;
    }
    __shared__ int h[NBUCKP];
    const int blk = blockIdx.x;
    for (int b = t; b < NBUCKP; b += 512) h[b] = 0;
    __syncthreads();
    const int ebase = blk * ECH + t * 16;
#pragma unroll
    for (int q = 0; q < 4; q++) {
        int e = ebase + q * 4;
        if (e + 4 <= NE) {
            int4 d4 = *reinterpret_cast<const int4*>(dst + e);
            atomicAdd(&h[d4.x >> BSH], 1);
            atomicAdd(&h[d4.y >> BSH], 1);
            atomicAdd(&h[d4.z >> BSH], 1);
            atomicAdd(&h[d4.w >> BSH], 1);
        } else {
            for (int p = e; p < NE; p++) atomicAdd(&h[dst[p] >> BSH], 1);
            break;
        }
    }
    __syncthreads();
    for (int b = t; b < NBUCK; b += 512) histT[(long long)b * NCHK + blk] = h[b];
}

// ---------------- per-bucket exclusive scan over chunks ----------------

__global__ __launch_bounds__(256) void k_scanb(int* __restrict__ histT,
                                               int* __restrict__ cntb) {
    __shared__ int s[256];
    const int b = blockIdx.x, t = threadIdx.x;
    int* row = histT + (long long)b * NCHK;
    int v = (t < NCHK) ? row[t] : 0;
    s[t] = v;
    __syncthreads();
    for (int off = 1; off < 256; off <<= 1) {
        int u = (t >= off) ? s[t - off] : 0;
        __syncthreads();
        s[t] += u;
        __syncthreads();
    }
    if (t < NCHK) row[t] = s[t] - v;
    if (t == 255) cntb[b] = s[255];
}

// ---------------- bucket partition scatter ----------------

__global__ __launch_bounds__(512) void k_part(const int* __restrict__ src,
                                              const int* __restrict__ dst,
                                              const int* __restrict__ histT,
                                              int* __restrict__ data) {
    __shared__ int curs[NBUCKP];
    const int t = threadIdx.x, blk = blockIdx.x;
    for (int b = t; b < NBUCKP; b += 512)
        curs[b] = b * CAP + ((b < NBUCK) ? histT[(long long)b * NCHK + blk] : 0);
    __syncthreads();
    const int ebase = blk * ECH + t * 16;
#pragma unroll
    for (int q = 0; q < 4; q++) {
        int e = ebase + q * 4;
        if (e + 4 <= NE) {
            int4 d4 = *reinterpret_cast<const int4*>(dst + e);
            int4 s4 = *reinterpret_cast<const int4*>(src + e);
            int p0 = atomicAdd(&curs[d4.x >> BSH], 1);
            data[p0] = (s4.x << BSH) | (d4.x & (BNODES - 1));
            int p1 = atomicAdd(&curs[d4.y >> BSH], 1);
            data[p1] = (s4.y << BSH) | (d4.y & (BNODES - 1));
            int p2 = atomicAdd(&curs[d4.z >> BSH], 1);
            data[p2] = (s4.z << BSH) | (d4.z & (BNODES - 1));
            int p3 = atomicAdd(&curs[d4.w >> BSH], 1);
            data[p3] = (s4.w << BSH) | (d4.w & (BNODES - 1));
        } else {
            for (int p = e; p < NE; p++) {
                int d = dst[p], sv = src[p];
                int pos = atomicAdd(&curs[d >> BSH], 1);
                data[pos] = (sv << BSH) | (d & (BNODES - 1));
            }
            break;
        }
    }
}

// ---------------- Layer 1: x -> h1 images; ILP-pinned pipeline ----------------
// 64 rows/block, 8 waves, wave w owns cols [32w,+32). W(kt+1) prefetched and
// order-pinned with sched_barrier(0) so loads stay ahead of MFMAs.

__global__ __launch_bounds__(512) void k_lay1(const float* __restrict__ x,
                                              const _Float16* __restrict__ Wf1,
                                              const float* __restrict__ b1,
                                              _Float16* __restrict__ h1g) {
    __shared__ char buf[64 * 512];  // 32 KB
    const int t = threadIdx.x;
    const int lane = t & 63;
    const int G = lane >> 4;
    const int w = t >> 6;
    const int T = blockIdx.x;
    const long long row0 = (long long)T * 64;

    const half8v* W1f = reinterpret_cast<const half8v*>(Wf1);
    float bvs[2];
#pragma unroll
    for (int n2 = 0; n2 < 2; n2++) bvs[n2] = b1[w * 32 + n2 * 16 + (lane & 15)];

    // prefetch kt=0 W frags (completes under staging)
    half8v bcur0 = W1f[(2 * w) * 64 + lane];
    half8v bcur1 = W1f[(2 * w + 1) * 64 + lane];

    // stage x tile: issue all 8 loads first (pinned), then convert+write
    {
        const float4* A4 = reinterpret_cast<const float4*>(x + row0 * 256);
        float4 v[8];
#pragma unroll
        for (int q = 0; q < 8; q++) {
            int i = t + q * 512;
            int r = i >> 6;
            v[q] = make_float4(0.f, 0.f, 0.f, 0.f);
            if (row0 + r < NN) v[q] = A4[i];
        }
        __builtin_amdgcn_sched_barrier(0);
#pragma unroll
        for (int q = 0; q < 8; q++) {
            int i = t + q * 512;
            int r = i >> 6, c4 = i & 63;
            half4v hv;
            hv[0] = (_Float16)v[q].x; hv[1] = (_Float16)v[q].y;
            hv[2] = (_Float16)v[q].z; hv[3] = (_Float16)v[q].w;
            int bo = (r * 512 + c4 * 8) ^ ((r & 7) << 4);
            *reinterpret_cast<half4v*>(buf + bo) = hv;
        }
    }
    __syncthreads();

    f32x4 acc[4][2];
#pragma unroll
    for (int mt = 0; mt < 4; mt++)
#pragma unroll
        for (int n2 = 0; n2 < 2; n2++) acc[mt][n2] = (f32x4)0.f;

#pragma unroll
    for (int kt = 0; kt < 8; kt++) {
        // issue next-kt W loads BEFORE this kt's compute; pin the order
        half8v bn0, bn1;
        if (kt < 7) {
            bn0 = W1f[((kt + 1) * 16 + 2 * w) * 64 + lane];
            bn1 = W1f[((kt + 1) * 16 + 2 * w + 1) * 64 + lane];
        }
        __builtin_amdgcn_sched_barrier(0);
        half8v a[4];
#pragma unroll
        for (int mt = 0; mt < 4; mt++) {
            int row = mt * 16 + (lane & 15);
            int bo = (row * 512 + kt * 64 + (G << 4)) ^ ((row & 7) << 4);
            a[mt] = *reinterpret_cast<const half8v*>(buf + bo);
        }
#pragma unroll
        for (int mt = 0; mt < 4; mt++) {
            acc[mt][0] = __builtin_amdgcn_mfma_f32_16x16x32_f16(a[mt], bcur0, acc[mt][0], 0, 0, 0);
            acc[mt][1] = __builtin_amdgcn_mfma_f32_16x16x32_f16(a[mt], bcur1, acc[mt][1], 0, 0, 0);
        }
        bcur0 = bn0;
        bcur1 = bn1;
    }
    __syncthreads();

    // bias+relu -> fp16 back into LDS (swizzled image)
#pragma unroll
    for (int mt = 0; mt < 4; mt++)
#pragma unroll
        for (int n2 = 0; n2 < 2; n2++) {
            int colc = w * 32 + n2 * 16 + (lane & 15);
            float bb = bvs[n2];
#pragma unroll
            for (int r = 0; r < 4; r++) {
                int row = mt * 16 + G * 4 + r;
                float v = fmaxf(acc[mt][n2][r] + bb, 0.f);
                int bo = (row * 512 + colc * 2) ^ ((row & 7) << 4);
                *reinterpret_cast<_Float16*>(buf + bo) = (_Float16)v;
            }
        }
    __syncthreads();

    // dump raw image -> global (issue 4 loads, then 4 stores)
    {
        half8v* dstp = reinterpret_cast<half8v*>(h1g + (size_t)T * 16384);
        const half8v* srcp = reinterpret_cast<const half8v*>(buf);
        half8v vv[4];
#pragma unroll
        for (int q = 0; q < 4; q++) vv[q] = srcp[t + q * 512];
        __builtin_amdgcn_sched_barrier(0);
#pragma unroll
        for (int q = 0; q < 4; q++) dstp[t + q * 512] = vv[q];
    }
}

// ---------------- per-bucket LDS counting sort -> CSR + dinv ----------------
// Own launch: k_lay23 reads dinv (R15 race lesson).

__global__ __launch_bounds__(256) void k_sortb(const int* __restrict__ data,
                                               const int* __restrict__ cntb,
                                               int* __restrict__ col,
                                               int* __restrict__ begp,
                                               int* __restrict__ endp,
                                               float* __restrict__ dinv) {
    __shared__ int hist[BNODES];
    __shared__ int scn[BNODES];
    __shared__ int curs[BNODES];
    const int b = blockIdx.x, t = threadIdx.x;
    if (t < BNODES) hist[t] = 0;
    __syncthreads();
    const int cnt = cntb[b];
    const int* wp = data + b * CAP;
    for (int e = t; e < cnt; e += 256) atomicAdd(&hist[wp[e] & (BNODES - 1)], 1);
    __syncthreads();
    if (t < BNODES) scn[t] = hist[t];
    __syncthreads();
    for (int off = 1; off < BNODES; off <<= 1) {
        int v = (t < BNODES && t >= off) ? scn[t - off] : 0;
        __syncthreads();
        if (t < BNODES) scn[t] += v;
        __syncthreads();
    }
    if (t < BNODES) {
        int beg = scn[t] - hist[t];
        curs[t] = beg;
        int node = (b << BSH) + t;
        if (node < NN) {
            begp[node] = b * CAP + beg;
            endp[node] = b * CAP + scn[t];
            dinv[node] = rsqrtf((float)(hist[t] + 1));
        }
    }
    __syncthreads();
    for (int e = t; e < cnt; e += 256) {
        int w = wp[e];
        int p = atomicAdd(&curs[w & (BNODES - 1)], 1);
        col[b * CAP + p] = w >> BSH;
    }
}

// ---------------- Layers 2+3: h1 image -> h0f, hs0; ILP-pinned ----------------

__global__ __launch_bounds__(512) void k_lay23(const _Float16* __restrict__ h1g,
                                               const _Float16* __restrict__ Wf2,
                                               const _Float16* __restrict__ Wf3,
                                               const float* __restrict__ b2,
                                               const float* __restrict__ b3,
                                               const float* __restrict__ dinv,
                                               _Float16* __restrict__ h0f,
                                               _Float16* __restrict__ hs0) {
    __shared__ char buf[64 * 512];  // 32 KB
    const int t = threadIdx.x;
    const int lane = t & 63;
    const int G = lane >> 4;
    const int w = t >> 6;
    const int T = blockIdx.x;
    const long long row0 = (long long)T * 64;

    const half8v* W2f = reinterpret_cast<const half8v*>(Wf2);
    float bvs[2];
#pragma unroll
    for (int n2 = 0; n2 < 2; n2++) bvs[n2] = b2[w * 32 + n2 * 16 + (lane & 15)];

    // prefetch kt=0 W frags
    half8v bcur0 = W2f[(2 * w) * 64 + lane];
    half8v bcur1 = W2f[(2 * w + 1) * 64 + lane];

    // stage h1 image: issue 4 loads, then 4 stores
    {
        const half8v* srcp = reinterpret_cast<const half8v*>(h1g + (size_t)T * 16384);
        half8v* dstp = reinterpret_cast<half8v*>(buf);
        half8v vv[4];
#pragma unroll
        for (int q = 0; q < 4; q++) vv[q] = srcp[t + q * 512];
        __builtin_amdgcn_sched_barrier(0);
#pragma unroll
        for (int q = 0; q < 4; q++) dstp[t + q * 512] = vv[q];
    }
    __syncthreads();

    // GEMM2 (pipelined W)
    f32x4 acc[4][2];
#pragma unroll
    for (int mt = 0; mt < 4; mt++)
#pragma unroll
        for (int n2 = 0; n2 < 2; n2++) acc[mt][n2] = (f32x4)0.f;

#pragma unroll
    for (int kt = 0; kt < 8; kt++) {
        half8v bn0, bn1;
        if (kt < 7) {
            bn0 = W2f[((kt + 1) * 16 + 2 * w) * 64 + lane];
            bn1 = W2f[((kt + 1) * 16 + 2 * w + 1) * 64 + lane];
        }
        __builtin_amdgcn_sched_barrier(0);
        half8v a[4];
#pragma unroll
        for (int mt = 0; mt < 4; mt++) {
            int row = mt * 16 + (lane & 15);
            int bo = (row * 512 + kt * 64 + (G << 4)) ^ ((row & 7) << 4);
            a[mt] = *reinterpret_cast<const half8v*>(buf + bo);
        }
#pragma unroll
        for (int mt = 0; mt < 4; mt++) {
            acc[mt][0] = __builtin_amdgcn_mfma_f32_16x16x32_f16(a[mt], bcur0, acc[mt][0], 0, 0, 0);
            acc[mt][1] = __builtin_amdgcn_mfma_f32_16x16x32_f16(a[mt], bcur1, acc[mt][1], 0, 0, 0);
        }
        bcur0 = bn0;
        bcur1 = bn1;
    }
    __syncthreads();

    // h2 -> LDS (swizzled fp16)
#pragma unroll
    for (int mt = 0; mt < 4; mt++)
#pragma unroll
        for (int n2 = 0; n2 < 2; n2++) {
            int colc = w * 32 + n2 * 16 + (lane & 15);
            float bb = bvs[n2];
#pragma unroll
            for (int r = 0; r < 4; r++) {
                int row = mt * 16 + G * 4 + r;
                float v = fmaxf(acc[mt][n2][r] + bb, 0.f);
                int bo = (row * 512 + colc * 2) ^ ((row & 7) << 4);
                *reinterpret_cast<_Float16*>(buf + bo) = (_Float16)v;
            }
        }
    __syncthreads();

    // GEMM3: 8 tiles, one per wave: mt3 = w>>1, ct3 = w&1
    {
        const half8v* W3f = reinterpret_cast<const half8v*>(Wf3);
        const int mt3 = w >> 1, ct3 = w & 1;
        const float bb3 = b3[ct3 * 16 + (lane & 15)];
        f32x4 a3 = (f32x4)0.f;
#pragma unroll
        for (int kt = 0; kt < 8; kt++) {
            int row = mt3 * 16 + (lane & 15);
            int bo = (row * 512 + kt * 64 + (G << 4)) ^ ((row & 7) << 4);
            half8v a = *reinterpret_cast<const half8v*>(buf + bo);
            half8v b = W3f[(kt * 2 + ct3) * 64 + lane];
            a3 = __builtin_amdgcn_mfma_f32_16x16x32_f16(a, b, a3, 0, 0, 0);
        }
        int colc = ct3 * 16 + (lane & 15);
#pragma unroll
        for (int r = 0; r < 4; r++) {
            long long row = row0 + mt3 * 16 + G * 4 + r;
            if (row < NN) {
                float v = a3[r] + bb3;
                h0f[row * 32 + colc] = (_Float16)v;
                hs0[row * 32 + colc] = (_Float16)(dinv[row] * v);
            }
        }
    }
}

// ---------------- fused APPNP step: one wave per node, 16 edges in flight ----------------

template<bool FINAL>
__global__ __launch_bounds__(256) void k_appnp(const int* __restrict__ begp,
                                               const int* __restrict__ endp,
                                               const int* __restrict__ col,
                                               const float* __restrict__ dinv,
                                               const _Float16* __restrict__ hs,
                                               const _Float16* __restrict__ h0f,
                                               void* __restrict__ outp) {
    int node = blockIdx.x * 4 + (threadIdx.x >> 6);
    if (node >= NN) return;
    const int lane = threadIdx.x & 63;
    const int slot = lane >> 2;
    const int cg = lane & 3;

    const int beg = begp[node];
    const int end = endp[node];
    const float dd = dinv[node];
    const half8v selfv = *reinterpret_cast<const half8v*>(hs + (size_t)node * 32 + cg * 8);
    const half8v h0v = *reinterpret_cast<const half8v*>(h0f + (size_t)node * 32 + cg * 8);

    float acc[8];
#pragma unroll
    for (int j = 0; j < 8; j++) acc[j] = 0.f;

    for (int e = beg + slot; e < end; e += 16) {
        int s = col[e];
        half8v v = *reinterpret_cast<const half8v*>(hs + (size_t)s * 32 + cg * 8);
#pragma unroll
        for (int j = 0; j < 8; j++) acc[j] += (float)v[j];
    }

#pragma unroll
    for (int off = 4; off < 64; off <<= 1) {
#pragma unroll
        for (int j = 0; j < 8; j++) acc[j] += __shfl_xor(acc[j], off, 64);
    }

    if (slot == 0) {
        float o[8];
#pragma unroll
        for (int j = 0; j < 8; j++)
            o[j] = 0.9f * dd * (acc[j] + (float)selfv[j]) + 0.1f * (float)h0v[j];
        size_t off = (size_t)node * 32 + cg * 8;
        if (FINAL) {
            float4 v0 = make_float4(o[0], o[1], o[2], o[3]);
            float4 v1 = make_float4(o[4], o[5], o[6], o[7]);
            float4* op = reinterpret_cast<float4*>((float*)outp + off);
            op[0] = v0; op[1] = v1;
        } else {
            half8v hv;
#pragma unroll
            for (int j = 0; j < 8; j++) hv[j] = (_Float16)(dd * o[j]);
            *reinterpret_cast<half8v*>((_Float16*)outp + off) = hv;
        }
    }
}

// ---------------- launch ----------------

extern "C" void kernel_launch(void* const* d_in, const int* in_sizes, int n_in,
                              void* d_out, int out_size, void* d_ws, size_t ws_size,
                              hipStream_t stream) {
    const float* x     = (const float*)d_in[0];
    const int*   ei    = (const int*)d_in[1];
    const float* W_in  = (const float*)d_in[2];
    const float* b_in  = (const float*)d_in[3];
    const float* W_h   = (const float*)d_in[4];
    const float* b_h   = (const float*)d_in[5];
    const float* W_out = (const float*)d_in[6];
    const float* b_out = (const float*)d_in[7];
    float* out = (float*)d_out;

    const int* srcv = ei;
    const int* dstv = ei + NE;

    char* ws = (char*)d_ws;
    _Float16* h0f  = (_Float16*)ws;                              // NN*32 f16
    _Float16* hs0  = h0f + (size_t)NN * 32;                      // NN*32 f16
    _Float16* hs1  = hs0 + (size_t)NN * 32;                      // NN*32 f16
    float* dinv    = (float*)(hs1 + (size_t)NN * 32);            // NN
    _Float16* Wf_in  = (_Float16*)(dinv + NN);                   // 256*256
    _Float16* Wf_h   = Wf_in + 256 * 256;                        // 256*256
    _Float16* Wf_out = Wf_h + 256 * 256;                         // 256*32
    _Float16* h1g    = Wf_out + 256 * 32;                        // NT64*16384 f16 (tile images)
    int* histT = (int*)(h1g + (size_t)NT64 * 16384);             // NBUCK*NCHK
    int* cntb  = histT + (size_t)NBUCK * NCHK;                   // NBUCKP
    int* data  = cntb + NBUCKP;                                  // NBUCKP*CAP
    int* col   = data + (size_t)NBUCKP * CAP;                    // NBUCKP*CAP
    int* begp  = col + (size_t)NBUCKP * CAP;                     // NN
    int* endp  = begp + NN;                                      // NN

    // --- [bucket count | W fragments] ---
    k_count_wfrag<<<NCHK + WFRAG_BLKS, 512, 0, stream>>>(dstv, histT,
                                                         W_in, W_h, W_out,
                                                         Wf_in, Wf_h, Wf_out);
    // --- per-bucket scan ---
    k_scanb<<<NBUCK, 256, 0, stream>>>(histT, cntb);

    // --- part scatter ---
    k_part<<<NCHK, 512, 0, stream>>>(srcv, dstv, histT, data);

    // --- layer 1 (pipelined) ---
    k_lay1<<<NT64, 512, 0, stream>>>(x, Wf_in, b_in, h1g);

    // --- per-bucket counting sort -> CSR + dinv ---
    k_sortb<<<NBUCK, 256, 0, stream>>>(data, cntb, col, begp, endp, dinv);

    // --- layers 2+3 (pipelined) ---
    k_lay23<<<NT64, 512, 0, stream>>>(h1g, Wf_h, Wf_out, b_h, b_out, dinv, h0f, hs0);

    // --- APPNP: K = 2 (wave-per-node, 16-wide gather) ---
    k_appnp<false><<<(NN + 3) / 4, 256, 0, stream>>>(begp, endp, col, dinv, hs0, h0f, hs1);
    k_appnp<true ><<<(NN + 3) / 4, 256, 0, stream>>>(begp, endp, col, dinv, hs1, h0f, out);
}

// Round 19
// 170.785 us; speedup vs baseline: 1.0086x; 1.0009x over previous
//
#include <hip/hip_runtime.h>

#define NN 100000
#define NE 1600000
#define NT64 1563    // ceil(NN / 64)

#define BSH 7
#define BNODES 128               // nodes per bucket
#define NBUCK 782                // ceil(NN / 128)
#define NBUCKP 784
#define CAP 2560                 // words per bucket region (exp 2048, +11 sigma)
#define ECH 8192                 // edges per chunk
#define NCHK 196                 // ceil(NE / ECH)
#define WFRAG_BLKS 272           // 139264 / 512

typedef _Float16 half8v __attribute__((ext_vector_type(8)));
typedef _Float16 half4v __attribute__((ext_vector_type(4)));
typedef float f32x4 __attribute__((ext_vector_type(4)));

// ---------------- W -> fp16 B-fragment layout ----------------
// Wf[((kt*(N/16)+nt)*64 + l)*8 + j] = W[(kt*32 + (l>>4)*8 + j)*N + nt*16 + (l&15)]

__device__ __forceinline__ void wfrag_one(const float* __restrict__ W,
                                          _Float16* __restrict__ Wf, int idx, int N) {
    int j = idx & 7;
    int l = (idx >> 3) & 63;
    int f = idx >> 9;
    int nt = f % (N / 16);
    int kt = f / (N / 16);
    int k = kt * 32 + (l >> 4) * 8 + j;
    int c = nt * 16 + (l & 15);
    Wf[idx] = (_Float16)W[k * N + c];
}

// ---------------- merged: bucket count (blocks 0..195) | wfrag (196..467) ----------------

__global__ __launch_bounds__(512) void k_count_wfrag(const int* __restrict__ dst,
                                                     int* __restrict__ histT,
                                                     const float* __restrict__ W1,
                                                     const float* __restrict__ W2,
                                                     const float* __restrict__ W3,
                                                     _Float16* __restrict__ Wf1,
                                                     _Float16* __restrict__ Wf2,
                                                     _Float16* __restrict__ Wf3) {
    const int t = threadIdx.x;
    if (blockIdx.x >= NCHK) {
        int idx = (blockIdx.x - NCHK) * 512 + t;
        if (idx < 65536) wfrag_one(W1, Wf1, idx, 256);
        else if (idx < 131072) wfrag_one(W2, Wf2, idx - 65536, 256);
        else if (idx < 139264) wfrag_one(W3, Wf3, idx - 131072, 32);
        return;
    }
    __shared__ int h[NBUCKP];
    const int blk = blockIdx.x;
    for (int b = t; b < NBUCKP; b += 512) h[b] = 0;
    __syncthreads();
    const int ebase = blk * ECH + t * 16;
#pragma unroll
    for (int q = 0; q < 4; q++) {
        int e = ebase + q * 4;
        if (e + 4 <= NE) {
            int4 d4 = *reinterpret_cast<const int4*>(dst + e);
            atomicAdd(&h[d4.x >> BSH], 1);
            atomicAdd(&h[d4.y >> BSH], 1);
            atomicAdd(&h[d4.z >> BSH], 1);
            atomicAdd(&h[d4.w >> BSH], 1);
        } else {
            for (int p = e; p < NE; p++) atomicAdd(&h[dst[p] >> BSH], 1);
            break;
        }
    }
    __syncthreads();
    for (int b = t; b < NBUCK; b += 512) histT[(long long)b * NCHK + blk] = h[b];
}

// ---------------- per-bucket exclusive scan over chunks ----------------

__global__ __launch_bounds__(256) void k_scanb(int* __restrict__ histT,
                                               int* __restrict__ cntb) {
    __shared__ int s[256];
    const int b = blockIdx.x, t = threadIdx.x;
    int* row = histT + (long long)b * NCHK;
    int v = (t < NCHK) ? row[t] : 0;
    s[t] = v;
    __syncthreads();
    for (int off = 1; off < 256; off <<= 1) {
        int u = (t >= off) ? s[t - off] : 0;
        __syncthreads();
        s[t] += u;
        __syncthreads();
    }
    if (t < NCHK) row[t] = s[t] - v;
    if (t == 255) cntb[b] = s[255];
}

// ---------------- bucket partition scatter ----------------

__global__ __launch_bounds__(512) void k_part(const int* __restrict__ src,
                                              const int* __restrict__ dst,
                                              const int* __restrict__ histT,
                                              int* __restrict__ data) {
    __shared__ int curs[NBUCKP];
    const int t = threadIdx.x, blk = blockIdx.x;
    for (int b = t; b < NBUCKP; b += 512)
        curs[b] = b * CAP + ((b < NBUCK) ? histT[(long long)b * NCHK + blk] : 0);
    __syncthreads();
    const int ebase = blk * ECH + t * 16;
#pragma unroll
    for (int q = 0; q < 4; q++) {
        int e = ebase + q * 4;
        if (e + 4 <= NE) {
            int4 d4 = *reinterpret_cast<const int4*>(dst + e);
            int4 s4 = *reinterpret_cast<const int4*>(src + e);
            int p0 = atomicAdd(&curs[d4.x >> BSH], 1);
            data[p0] = (s4.x << BSH) | (d4.x & (BNODES - 1));
            int p1 = atomicAdd(&curs[d4.y >> BSH], 1);
            data[p1] = (s4.y << BSH) | (d4.y & (BNODES - 1));
            int p2 = atomicAdd(&curs[d4.z >> BSH], 1);
            data[p2] = (s4.z << BSH) | (d4.z & (BNODES - 1));
            int p3 = atomicAdd(&curs[d4.w >> BSH], 1);
            data[p3] = (s4.w << BSH) | (d4.w & (BNODES - 1));
        } else {
            for (int p = e; p < NE; p++) {
                int d = dst[p], sv = src[p];
                int pos = atomicAdd(&curs[d >> BSH], 1);
                data[pos] = (sv << BSH) | (d & (BNODES - 1));
            }
            break;
        }
    }
}

// ---------------- per-bucket LDS counting sort -> CSR + dinv ----------------
// Own launch: k_mlp reads dinv (R15 race lesson).

__global__ __launch_bounds__(256) void k_sortb(const int* __restrict__ data,
                                               const int* __restrict__ cntb,
                                               int* __restrict__ col,
                                               int* __restrict__ begp,
                                               int* __restrict__ endp,
                                               float* __restrict__ dinv) {
    __shared__ int hist[BNODES];
    __shared__ int scn[BNODES];
    __shared__ int curs[BNODES];
    const int b = blockIdx.x, t = threadIdx.x;
    if (t < BNODES) hist[t] = 0;
    __syncthreads();
    const int cnt = cntb[b];
    const int* wp = data + b * CAP;
    for (int e = t; e < cnt; e += 256) atomicAdd(&hist[wp[e] & (BNODES - 1)], 1);
    __syncthreads();
    if (t < BNODES) scn[t] = hist[t];
    __syncthreads();
    for (int off = 1; off < BNODES; off <<= 1) {
        int v = (t < BNODES && t >= off) ? scn[t - off] : 0;
        __syncthreads();
        if (t < BNODES) scn[t] += v;
        __syncthreads();
    }
    if (t < BNODES) {
        int beg = scn[t] - hist[t];
        curs[t] = beg;
        int node = (b << BSH) + t;
        if (node < NN) {
            begp[node] = b * CAP + beg;
            endp[node] = b * CAP + scn[t];
            dinv[node] = rsqrtf((float)(hist[t] + 1));
        }
    }
    __syncthreads();
    for (int e = t; e < cnt; e += 256) {
        int w = wp[e];
        int p = atomicAdd(&curs[w & (BNODES - 1)], 1);
        col[b * CAP + p] = w >> BSH;
    }
}

// ---------------- fused MLP: x -> h0f, hs0 in ONE kernel ----------------
// 64 rows/block, 8 waves, single 32KB LDS buffer (read-all -> barrier ->
// write-in-place). No h1 global round trip. Runs AFTER k_sortb (reads dinv).

__global__ __launch_bounds__(512) void k_mlp(const float* __restrict__ x,
                                             const _Float16* __restrict__ Wf1,
                                             const _Float16* __restrict__ Wf2,
                                             const _Float16* __restrict__ Wf3,
                                             const float* __restrict__ b1,
                                             const float* __restrict__ b2,
                                             const float* __restrict__ b3,
                                             const float* __restrict__ dinv,
                                             _Float16* __restrict__ h0f,
                                             _Float16* __restrict__ hs0) {
    __shared__ char buf[64 * 512];  // 32 KB, reused by all phases
    const int t = threadIdx.x;
    const int lane = t & 63;
    const int G = lane >> 4;
    const int w = t >> 6;
    const int T = blockIdx.x;
    const long long row0 = (long long)T * 64;

    const half8v* W1f = reinterpret_cast<const half8v*>(Wf1);
    const half8v* W2f = reinterpret_cast<const half8v*>(Wf2);
    float bv1[2], bv2[2];
#pragma unroll
    for (int n2 = 0; n2 < 2; n2++) {
        bv1[n2] = b1[w * 32 + n2 * 16 + (lane & 15)];
        bv2[n2] = b2[w * 32 + n2 * 16 + (lane & 15)];
    }

    // ---- stage x tile fp32 -> fp16 swizzled (issue loads first) ----
    {
        const float4* A4 = reinterpret_cast<const float4*>(x + row0 * 256);
        float4 v[8];
#pragma unroll
        for (int q = 0; q < 8; q++) {
            int i = t + q * 512;
            int r = i >> 6;
            v[q] = make_float4(0.f, 0.f, 0.f, 0.f);
            if (row0 + r < NN) v[q] = A4[i];
        }
        __builtin_amdgcn_sched_barrier(0);
#pragma unroll
        for (int q = 0; q < 8; q++) {
            int i = t + q * 512;
            int r = i >> 6, c4 = i & 63;
            half4v hv;
            hv[0] = (_Float16)v[q].x; hv[1] = (_Float16)v[q].y;
            hv[2] = (_Float16)v[q].z; hv[3] = (_Float16)v[q].w;
            int bo = (r * 512 + c4 * 8) ^ ((r & 7) << 4);
            *reinterpret_cast<half4v*>(buf + bo) = hv;
        }
    }
    __syncthreads();

    f32x4 acc[4][2];

    // ---- GEMM1: read x image, accumulate ----
#pragma unroll
    for (int mt = 0; mt < 4; mt++)
#pragma unroll
        for (int n2 = 0; n2 < 2; n2++) acc[mt][n2] = (f32x4)0.f;
#pragma unroll
    for (int kt = 0; kt < 8; kt++) {
        half8v a[4], bfr[2];
#pragma unroll
        for (int n2 = 0; n2 < 2; n2++)
            bfr[n2] = W1f[(kt * 16 + 2 * w + n2) * 64 + lane];
#pragma unroll
        for (int mt = 0; mt < 4; mt++) {
            int row = mt * 16 + (lane & 15);
            int bo = (row * 512 + kt * 64 + (G << 4)) ^ ((row & 7) << 4);
            a[mt] = *reinterpret_cast<const half8v*>(buf + bo);
        }
#pragma unroll
        for (int mt = 0; mt < 4; mt++)
#pragma unroll
            for (int n2 = 0; n2 < 2; n2++)
                acc[mt][n2] = __builtin_amdgcn_mfma_f32_16x16x32_f16(a[mt], bfr[n2], acc[mt][n2], 0, 0, 0);
    }
    __syncthreads();

    // ---- h1 = relu(acc + b1) -> LDS in place ----
#pragma unroll
    for (int mt = 0; mt < 4; mt++)
#pragma unroll
        for (int n2 = 0; n2 < 2; n2++) {
            int colc = w * 32 + n2 * 16 + (lane & 15);
            float bb = bv1[n2];
#pragma unroll
            for (int r = 0; r < 4; r++) {
                int row = mt * 16 + G * 4 + r;
                float v = fmaxf(acc[mt][n2][r] + bb, 0.f);
                int bo = (row * 512 + colc * 2) ^ ((row & 7) << 4);
                *reinterpret_cast<_Float16*>(buf + bo) = (_Float16)v;
            }
        }
    __syncthreads();

    // ---- GEMM2: read h1 image, accumulate ----
#pragma unroll
    for (int mt = 0; mt < 4; mt++)
#pragma unroll
        for (int n2 = 0; n2 < 2; n2++) acc[mt][n2] = (f32x4)0.f;
#pragma unroll
    for (int kt = 0; kt < 8; kt++) {
        half8v a[4], bfr[2];
#pragma unroll
        for (int n2 = 0; n2 < 2; n2++)
            bfr[n2] = W2f[(kt * 16 + 2 * w + n2) * 64 + lane];
#pragma unroll
        for (int mt = 0; mt < 4; mt++) {
            int row = mt * 16 + (lane & 15);
            int bo = (row * 512 + kt * 64 + (G << 4)) ^ ((row & 7) << 4);
            a[mt] = *reinterpret_cast<const half8v*>(buf + bo);
        }
#pragma unroll
        for (int mt = 0; mt < 4; mt++)
#pragma unroll
            for (int n2 = 0; n2 < 2; n2++)
                acc[mt][n2] = __builtin_amdgcn_mfma_f32_16x16x32_f16(a[mt], bfr[n2], acc[mt][n2], 0, 0, 0);
    }
    __syncthreads();

    // ---- h2 = relu(acc + b2) -> LDS in place ----
#pragma unroll
    for (int mt = 0; mt < 4; mt++)
#pragma unroll
        for (int n2 = 0; n2 < 2; n2++) {
            int colc = w * 32 + n2 * 16 + (lane & 15);
            float bb = bv2[n2];
#pragma unroll
            for (int r = 0; r < 4; r++) {
                int row = mt * 16 + G * 4 + r;
                float v = fmaxf(acc[mt][n2][r] + bb, 0.f);
                int bo = (row * 512 + colc * 2) ^ ((row & 7) << 4);
                *reinterpret_cast<_Float16*>(buf + bo) = (_Float16)v;
            }
        }
    __syncthreads();

    // ---- GEMM3: 64x256 @ 256x32 = 8 16x16 tiles, one per wave ----
    {
        const half8v* W3f = reinterpret_cast<const half8v*>(Wf3);
        const int mt3 = w >> 1, ct3 = w & 1;
        const float bb3 = b3[ct3 * 16 + (lane & 15)];
        f32x4 a3 = (f32x4)0.f;
#pragma unroll
        for (int kt = 0; kt < 8; kt++) {
            int row = mt3 * 16 + (lane & 15);
            int bo = (row * 512 + kt * 64 + (G << 4)) ^ ((row & 7) << 4);
            half8v a = *reinterpret_cast<const half8v*>(buf + bo);
            half8v b = W3f[(kt * 2 + ct3) * 64 + lane];
            a3 = __builtin_amdgcn_mfma_f32_16x16x32_f16(a, b, a3, 0, 0, 0);
        }
        int colc = ct3 * 16 + (lane & 15);
#pragma unroll
        for (int r = 0; r < 4; r++) {
            long long row = row0 + mt3 * 16 + G * 4 + r;
            if (row < NN) {
                float v = a3[r] + bb3;
                h0f[row * 32 + colc] = (_Float16)v;
                hs0[row * 32 + colc] = (_Float16)(dinv[row] * v);
            }
        }
    }
}

// ---------------- fused APPNP step: one wave per node, 16 edges in flight ----------------

template<bool FINAL>
__global__ __launch_bounds__(256) void k_appnp(const int* __restrict__ begp,
                                               const int* __restrict__ endp,
                                               const int* __restrict__ col,
                                               const float* __restrict__ dinv,
                                               const _Float16* __restrict__ hs,
                                               const _Float16* __restrict__ h0f,
                                               void* __restrict__ outp) {
    int node = blockIdx.x * 4 + (threadIdx.x >> 6);
    if (node >= NN) return;
    const int lane = threadIdx.x & 63;
    const int slot = lane >> 2;
    const int cg = lane & 3;

    const int beg = begp[node];
    const int end = endp[node];
    const float dd = dinv[node];
    const half8v selfv = *reinterpret_cast<const half8v*>(hs + (size_t)node * 32 + cg * 8);
    const half8v h0v = *reinterpret_cast<const half8v*>(h0f + (size_t)node * 32 + cg * 8);

    float acc[8];
#pragma unroll
    for (int j = 0; j < 8; j++) acc[j] = 0.f;

    for (int e = beg + slot; e < end; e += 16) {
        int s = col[e];
        half8v v = *reinterpret_cast<const half8v*>(hs + (size_t)s * 32 + cg * 8);
#pragma unroll
        for (int j = 0; j < 8; j++) acc[j] += (float)v[j];
    }

#pragma unroll
    for (int off = 4; off < 64; off <<= 1) {
#pragma unroll
        for (int j = 0; j < 8; j++) acc[j] += __shfl_xor(acc[j], off, 64);
    }

    if (slot == 0) {
        float o[8];
#pragma unroll
        for (int j = 0; j < 8; j++)
            o[j] = 0.9f * dd * (acc[j] + (float)selfv[j]) + 0.1f * (float)h0v[j];
        size_t off = (size_t)node * 32 + cg * 8;
        if (FINAL) {
            float4 v0 = make_float4(o[0], o[1], o[2], o[3]);
            float4 v1 = make_float4(o[4], o[5], o[6], o[7]);
            float4* op = reinterpret_cast<float4*>((float*)outp + off);
            op[0] = v0; op[1] = v1;
        } else {
            half8v hv;
#pragma unroll
            for (int j = 0; j < 8; j++) hv[j] = (_Float16)(dd * o[j]);
            *reinterpret_cast<half8v*>((_Float16*)outp + off) = hv;
        }
    }
}

// ---------------- launch ----------------

extern "C" void kernel_launch(void* const* d_in, const int* in_sizes, int n_in,
                              void* d_out, int out_size, void* d_ws, size_t ws_size,
                              hipStream_t stream) {
    const float* x     = (const float*)d_in[0];
    const int*   ei    = (const int*)d_in[1];
    const float* W_in  = (const float*)d_in[2];
    const float* b_in  = (const float*)d_in[3];
    const float* W_h   = (const float*)d_in[4];
    const float* b_h   = (const float*)d_in[5];
    const float* W_out = (const float*)d_in[6];
    const float* b_out = (const float*)d_in[7];
    float* out = (float*)d_out;

    const int* srcv = ei;
    const int* dstv = ei + NE;

    char* ws = (char*)d_ws;
    _Float16* h0f  = (_Float16*)ws;                              // NN*32 f16
    _Float16* hs0  = h0f + (size_t)NN * 32;                      // NN*32 f16
    _Float16* hs1  = hs0 + (size_t)NN * 32;                      // NN*32 f16
    float* dinv    = (float*)(hs1 + (size_t)NN * 32);            // NN
    _Float16* Wf_in  = (_Float16*)(dinv + NN);                   // 256*256
    _Float16* Wf_h   = Wf_in + 256 * 256;                        // 256*256
    _Float16* Wf_out = Wf_h + 256 * 256;                         // 256*32
    int* histT = (int*)(Wf_out + 256 * 32);                      // NBUCK*NCHK
    int* cntb  = histT + (size_t)NBUCK * NCHK;                   // NBUCKP
    int* data  = cntb + NBUCKP;                                  // NBUCKP*CAP
    int* col   = data + (size_t)NBUCKP * CAP;                    // NBUCKP*CAP
    int* begp  = col + (size_t)NBUCKP * CAP;                     // NN
    int* endp  = begp + NN;                                      // NN

    // --- [bucket count | W fragments] ---
    k_count_wfrag<<<NCHK + WFRAG_BLKS, 512, 0, stream>>>(dstv, histT,
                                                         W_in, W_h, W_out,
                                                         Wf_in, Wf_h, Wf_out);
    // --- per-bucket scan ---
    k_scanb<<<NBUCK, 256, 0, stream>>>(histT, cntb);

    // --- part scatter ---
    k_part<<<NCHK, 512, 0, stream>>>(srcv, dstv, histT, data);

    // --- per-bucket counting sort -> CSR + dinv ---
    k_sortb<<<NBUCK, 256, 0, stream>>>(data, cntb, col, begp, endp, dinv);

    // --- fused MLP (x -> h0f, hs0); after sortb (reads dinv) ---
    k_mlp<<<NT64, 512, 0, stream>>>(x, Wf_in, Wf_h, Wf_out, b_in, b_h, b_out,
                                    dinv, h0f, hs0);

    // --- APPNP: K = 2 (wave-per-node, 16-wide gather) ---
    k_appnp<false><<<(NN + 3) / 4, 256, 0, stream>>>(begp, endp, col, dinv, hs0, h0f, hs1);
    k_appnp<true ><<<(NN + 3) / 4, 256, 0, stream>>>(begp, endp, col, dinv, hs1, h0f, out);
}

// Round 20
// 170.717 us; speedup vs baseline: 1.0090x; 1.0004x over previous
//
#include <hip/hip_runtime.h>

#define NN 100000
#define NE 1600000
#define NT64 1563    // ceil(NN / 64)

#define BSH 7
#define BNODES 128               // nodes per bucket
#define NBUCK 782                // ceil(NN / 128)
#define NBUCKP 784
#define CAP 2560                 // words per bucket region (exp 2048, +11 sigma)
#define ECH 8192                 // edges per chunk
#define NCHK 196                 // ceil(NE / ECH)
#define WFRAG_BLKS 272           // 139264 / 512

typedef _Float16 half8v __attribute__((ext_vector_type(8)));
typedef _Float16 half4v __attribute__((ext_vector_type(4)));
typedef float f32x4 __attribute__((ext_vector_type(4)));

// ---------------- W -> fp16 B-fragment layout ----------------
// Wf[((kt*(N/16)+nt)*64 + l)*8 + j] = W[(kt*32 + (l>>4)*8 + j)*N + nt*16 + (l&15)]

__device__ __forceinline__ void wfrag_one(const float* __restrict__ W,
                                          _Float16* __restrict__ Wf, int idx, int N) {
    int j = idx & 7;
    int l = (idx >> 3) & 63;
    int f = idx >> 9;
    int nt = f % (N / 16);
    int kt = f / (N / 16);
    int k = kt * 32 + (l >> 4) * 8 + j;
    int c = nt * 16 + (l & 15);
    Wf[idx] = (_Float16)W[k * N + c];
}

// ---------------- merged: bucket count (blocks 0..195) | wfrag (196..467) ----------------

__global__ __launch_bounds__(512) void k_count_wfrag(const int* __restrict__ dst,
                                                     int* __restrict__ histT,
                                                     const float* __restrict__ W1,
                                                     const float* __restrict__ W2,
                                                     const float* __restrict__ W3,
                                                     _Float16* __restrict__ Wf1,
                                                     _Float16* __restrict__ Wf2,
                                                     _Float16* __restrict__ Wf3) {
    const int t = threadIdx.x;
    if (blockIdx.x >= NCHK) {
        int idx = (blockIdx.x - NCHK) * 512 + t;
        if (idx < 65536) wfrag_one(W1, Wf1, idx, 256);
        else if (idx < 131072) wfrag_one(W2, Wf2, idx - 65536, 256);
        else if (idx < 139264) wfrag_one(W3, Wf3, idx - 131072, 32);
        return;
    }
    __shared__ int h[NBUCKP];
    const int blk = blockIdx.x;
    for (int b = t; b < NBUCKP; b += 512) h[b] = 0;
    __syncthreads();
    const int ebase = blk * ECH + t * 16;
#pragma unroll
    for (int q = 0; q < 4; q++) {
        int e = ebase + q * 4;
        if (e + 4 <= NE) {
            int4 d4 = *reinterpret_cast<const int4*>(dst + e);
            atomicAdd(&h[d4.x >> BSH], 1);
            atomicAdd(&h[d4.y >> BSH], 1);
            atomicAdd(&h[d4.z >> BSH], 1);
            atomicAdd(&h[d4.w >> BSH], 1);
        } else {
            for (int p = e; p < NE; p++) atomicAdd(&h[dst[p] >> BSH], 1);
            break;
        }
    }
    __syncthreads();
    for (int b = t; b < NBUCK; b += 512) histT[(long long)b * NCHK + blk] = h[b];
}

// ---------------- per-bucket exclusive scan over chunks ----------------

__global__ __launch_bounds__(256) void k_scanb(int* __restrict__ histT,
                                               int* __restrict__ cntb) {
    __shared__ int s[256];
    const int b = blockIdx.x, t = threadIdx.x;
    int* row = histT + (long long)b * NCHK;
    int v = (t < NCHK) ? row[t] : 0;
    s[t] = v;
    __syncthreads();
    for (int off = 1; off < 256; off <<= 1) {
        int u = (t >= off) ? s[t - off] : 0;
        __syncthreads();
        s[t] += u;
        __syncthreads();
    }
    if (t < NCHK) row[t] = s[t] - v;
    if (t == 255) cntb[b] = s[255];
}

// ---------------- bucket partition scatter ----------------

__global__ __launch_bounds__(512) void k_part(const int* __restrict__ src,
                                              const int* __restrict__ dst,
                                              const int* __restrict__ histT,
                                              int* __restrict__ data) {
    __shared__ int curs[NBUCKP];
    const int t = threadIdx.x, blk = blockIdx.x;
    for (int b = t; b < NBUCKP; b += 512)
        curs[b] = b * CAP + ((b < NBUCK) ? histT[(long long)b * NCHK + blk] : 0);
    __syncthreads();
    const int ebase = blk * ECH + t * 16;
#pragma unroll
    for (int q = 0; q < 4; q++) {
        int e = ebase + q * 4;
        if (e + 4 <= NE) {
            int4 d4 = *reinterpret_cast<const int4*>(dst + e);
            int4 s4 = *reinterpret_cast<const int4*>(src + e);
            int p0 = atomicAdd(&curs[d4.x >> BSH], 1);
            data[p0] = (s4.x << BSH) | (d4.x & (BNODES - 1));
            int p1 = atomicAdd(&curs[d4.y >> BSH], 1);
            data[p1] = (s4.y << BSH) | (d4.y & (BNODES - 1));
            int p2 = atomicAdd(&curs[d4.z >> BSH], 1);
            data[p2] = (s4.z << BSH) | (d4.z & (BNODES - 1));
            int p3 = atomicAdd(&curs[d4.w >> BSH], 1);
            data[p3] = (s4.w << BSH) | (d4.w & (BNODES - 1));
        } else {
            for (int p = e; p < NE; p++) {
                int d = dst[p], sv = src[p];
                int pos = atomicAdd(&curs[d >> BSH], 1);
                data[pos] = (sv << BSH) | (d & (BNODES - 1));
            }
            break;
        }
    }
}

// ---------------- per-bucket LDS counting sort -> CSR + dinv ----------------
// Own launch: k_mlp reads dinv (R15 race lesson).

__global__ __launch_bounds__(256) void k_sortb(const int* __restrict__ data,
                                               const int* __restrict__ cntb,
                                               int* __restrict__ col,
                                               int* __restrict__ begp,
                                               int* __restrict__ endp,
                                               float* __restrict__ dinv) {
    __shared__ int hist[BNODES];
    __shared__ int scn[BNODES];
    __shared__ int curs[BNODES];
    const int b = blockIdx.x, t = threadIdx.x;
    if (t < BNODES) hist[t] = 0;
    __syncthreads();
    const int cnt = cntb[b];
    const int* wp = data + b * CAP;
    for (int e = t; e < cnt; e += 256) atomicAdd(&hist[wp[e] & (BNODES - 1)], 1);
    __syncthreads();
    if (t < BNODES) scn[t] = hist[t];
    __syncthreads();
    for (int off = 1; off < BNODES; off <<= 1) {
        int v = (t < BNODES && t >= off) ? scn[t - off] : 0;
        __syncthreads();
        if (t < BNODES) scn[t] += v;
        __syncthreads();
    }
    if (t < BNODES) {
        int beg = scn[t] - hist[t];
        curs[t] = beg;
        int node = (b << BSH) + t;
        if (node < NN) {
            begp[node] = b * CAP + beg;
            endp[node] = b * CAP + scn[t];
            dinv[node] = rsqrtf((float)(hist[t] + 1));
        }
    }
    __syncthreads();
    for (int e = t; e < cnt; e += 256) {
        int w = wp[e];
        int p = atomicAdd(&curs[w & (BNODES - 1)], 1);
        col[b * CAP + p] = w >> BSH;
    }
}

// ---------------- fused MLP: x -> h0f, hs0 in ONE kernel ----------------
// 64 rows/block, 8 waves, single 32KB LDS buffer (read-all -> barrier ->
// write-in-place). No h1 global round trip. Runs AFTER k_sortb (reads dinv).

__global__ __launch_bounds__(512) void k_mlp(const float* __restrict__ x,
                                             const _Float16* __restrict__ Wf1,
                                             const _Float16* __restrict__ Wf2,
                                             const _Float16* __restrict__ Wf3,
                                             const float* __restrict__ b1,
                                             const float* __restrict__ b2,
                                             const float* __restrict__ b3,
                                             const float* __restrict__ dinv,
                                             _Float16* __restrict__ h0f,
                                             _Float16* __restrict__ hs0) {
    __shared__ char buf[64 * 512];  // 32 KB, reused by all phases
    const int t = threadIdx.x;
    const int lane = t & 63;
    const int G = lane >> 4;
    const int w = t >> 6;
    const int T = blockIdx.x;
    const long long row0 = (long long)T * 64;

    const half8v* W1f = reinterpret_cast<const half8v*>(Wf1);
    const half8v* W2f = reinterpret_cast<const half8v*>(Wf2);
    float bv1[2], bv2[2];
#pragma unroll
    for (int n2 = 0; n2 < 2; n2++) {
        bv1[n2] = b1[w * 32 + n2 * 16 + (lane & 15)];
        bv2[n2] = b2[w * 32 + n2 * 16 + (lane & 15)];
    }

    // ---- stage x tile fp32 -> fp16 swizzled (issue loads first) ----
    {
        const float4* A4 = reinterpret_cast<const float4*>(x + row0 * 256);
        float4 v[8];
#pragma unroll
        for (int q = 0; q < 8; q++) {
            int i = t + q * 512;
            int r = i >> 6;
            v[q] = make_float4(0.f, 0.f, 0.f, 0.f);
            if (row0 + r < NN) v[q] = A4[i];
        }
        __builtin_amdgcn_sched_barrier(0);
#pragma unroll
        for (int q = 0; q < 8; q++) {
            int i = t + q * 512;
            int r = i >> 6, c4 = i & 63;
            half4v hv;
            hv[0] = (_Float16)v[q].x; hv[1] = (_Float16)v[q].y;
            hv[2] = (_Float16)v[q].z; hv[3] = (_Float16)v[q].w;
            int bo = (r * 512 + c4 * 8) ^ ((r & 7) << 4);
            *reinterpret_cast<half4v*>(buf + bo) = hv;
        }
    }
    __syncthreads();

    f32x4 acc[4][2];

    // ---- GEMM1: read x image, accumulate ----
#pragma unroll
    for (int mt = 0; mt < 4; mt++)
#pragma unroll
        for (int n2 = 0; n2 < 2; n2++) acc[mt][n2] = (f32x4)0.f;
#pragma unroll
    for (int kt = 0; kt < 8; kt++) {
        half8v a[4], bfr[2];
#pragma unroll
        for (int n2 = 0; n2 < 2; n2++)
            bfr[n2] = W1f[(kt * 16 + 2 * w + n2) * 64 + lane];
#pragma unroll
        for (int mt = 0; mt < 4; mt++) {
            int row = mt * 16 + (lane & 15);
            int bo = (row * 512 + kt * 64 + (G << 4)) ^ ((row & 7) << 4);
            a[mt] = *reinterpret_cast<const half8v*>(buf + bo);
        }
#pragma unroll
        for (int mt = 0; mt < 4; mt++)
#pragma unroll
            for (int n2 = 0; n2 < 2; n2++)
                acc[mt][n2] = __builtin_amdgcn_mfma_f32_16x16x32_f16(a[mt], bfr[n2], acc[mt][n2], 0, 0, 0);
    }
    __syncthreads();

    // ---- h1 = relu(acc + b1) -> LDS in place ----
#pragma unroll
    for (int mt = 0; mt < 4; mt++)
#pragma unroll
        for (int n2 = 0; n2 < 2; n2++) {
            int colc = w * 32 + n2 * 16 + (lane & 15);
            float bb = bv1[n2];
#pragma unroll
            for (int r = 0; r < 4; r++) {
                int row = mt * 16 + G * 4 + r;
                float v = fmaxf(acc[mt][n2][r] + bb, 0.f);
                int bo = (row * 512 + colc * 2) ^ ((row & 7) << 4);
                *reinterpret_cast<_Float16*>(buf + bo) = (_Float16)v;
            }
        }
    __syncthreads();

    // ---- GEMM2: read h1 image, accumulate ----
#pragma unroll
    for (int mt = 0; mt < 4; mt++)
#pragma unroll
        for (int n2 = 0; n2 < 2; n2++) acc[mt][n2] = (f32x4)0.f;
#pragma unroll
    for (int kt = 0; kt < 8; kt++) {
        half8v a[4], bfr[2];
#pragma unroll
        for (int n2 = 0; n2 < 2; n2++)
            bfr[n2] = W2f[(kt * 16 + 2 * w + n2) * 64 + lane];
#pragma unroll
        for (int mt = 0; mt < 4; mt++) {
            int row = mt * 16 + (lane & 15);
            int bo = (row * 512 + kt * 64 + (G << 4)) ^ ((row & 7) << 4);
            a[mt] = *reinterpret_cast<const half8v*>(buf + bo);
        }
#pragma unroll
        for (int mt = 0; mt < 4; mt++)
#pragma unroll
            for (int n2 = 0; n2 < 2; n2++)
                acc[mt][n2] = __builtin_amdgcn_mfma_f32_16x16x32_f16(a[mt], bfr[n2], acc[mt][n2], 0, 0, 0);
    }
    __syncthreads();

    // ---- h2 = relu(acc + b2) -> LDS in place ----
#pragma unroll
    for (int mt = 0; mt < 4; mt++)
#pragma unroll
        for (int n2 = 0; n2 < 2; n2++) {
            int colc = w * 32 + n2 * 16 + (lane & 15);
            float bb = bv2[n2];
#pragma unroll
            for (int r = 0; r < 4; r++) {
                int row = mt * 16 + G * 4 + r;
                float v = fmaxf(acc[mt][n2][r] + bb, 0.f);
                int bo = (row * 512 + colc * 2) ^ ((row & 7) << 4);
                *reinterpret_cast<_Float16*>(buf + bo) = (_Float16)v;
            }
        }
    __syncthreads();

    // ---- GEMM3: 64x256 @ 256x32 = 8 16x16 tiles, one per wave ----
    {
        const half8v* W3f = reinterpret_cast<const half8v*>(Wf3);
        const int mt3 = w >> 1, ct3 = w & 1;
        const float bb3 = b3[ct3 * 16 + (lane & 15)];
        f32x4 a3 = (f32x4)0.f;
#pragma unroll
        for (int kt = 0; kt < 8; kt++) {
            int row = mt3 * 16 + (lane & 15);
            int bo = (row * 512 + kt * 64 + (G << 4)) ^ ((row & 7) << 4);
            half8v a = *reinterpret_cast<const half8v*>(buf + bo);
            half8v b = W3f[(kt * 2 + ct3) * 64 + lane];
            a3 = __builtin_amdgcn_mfma_f32_16x16x32_f16(a, b, a3, 0, 0, 0);
        }
        int colc = ct3 * 16 + (lane & 15);
#pragma unroll
        for (int r = 0; r < 4; r++) {
            long long row = row0 + mt3 * 16 + G * 4 + r;
            if (row < NN) {
                float v = a3[r] + bb3;
                h0f[row * 32 + colc] = (_Float16)v;
                hs0[row * 32 + colc] = (_Float16)(dinv[row] * v);
            }
        }
    }
}

// ---------------- fused APPNP step: one wave per node, 16 edges in flight ----------------

template<bool FINAL>
__global__ __launch_bounds__(256) void k_appnp(const int* __restrict__ begp,
                                               const int* __restrict__ endp,
                                               const int* __restrict__ col,
                                               const float* __restrict__ dinv,
                                               const _Float16* __restrict__ hs,
                                               const _Float16* __restrict__ h0f,
                                               void* __restrict__ outp) {
    int node = blockIdx.x * 4 + (threadIdx.x >> 6);
    if (node >= NN) return;
    const int lane = threadIdx.x & 63;
    const int slot = lane >> 2;
    const int cg = lane & 3;

    const int beg = begp[node];
    const int end = endp[node];
    const float dd = dinv[node];
    const half8v selfv = *reinterpret_cast<const half8v*>(hs + (size_t)node * 32 + cg * 8);
    const half8v h0v = *reinterpret_cast<const half8v*>(h0f + (size_t)node * 32 + cg * 8);

    float acc[8];
#pragma unroll
    for (int j = 0; j < 8; j++) acc[j] = 0.f;

    for (int e = beg + slot; e < end; e += 16) {
        int s = col[e];
        half8v v = *reinterpret_cast<const half8v*>(hs + (size_t)s * 32 + cg * 8);
#pragma unroll
        for (int j = 0; j < 8; j++) acc[j] += (float)v[j];
    }

#pragma unroll
    for (int off = 4; off < 64; off <<= 1) {
#pragma unroll
        for (int j = 0; j < 8; j++) acc[j] += __shfl_xor(acc[j], off, 64);
    }

    if (slot == 0) {
        float o[8];
#pragma unroll
        for (int j = 0; j < 8; j++)
            o[j] = 0.9f * dd * (acc[j] + (float)selfv[j]) + 0.1f * (float)h0v[j];
        size_t off = (size_t)node * 32 + cg * 8;
        if (FINAL) {
            float4 v0 = make_float4(o[0], o[1], o[2], o[3]);
            float4 v1 = make_float4(o[4], o[5], o[6], o[7]);
            float4* op = reinterpret_cast<float4*>((float*)outp + off);
            op[0] = v0; op[1] = v1;
        } else {
            half8v hv;
#pragma unroll
            for (int j = 0; j < 8; j++) hv[j] = (_Float16)(dd * o[j]);
            *reinterpret_cast<half8v*>((_Float16*)outp + off) = hv;
        }
    }
}

// ---------------- launch ----------------

extern "C" void kernel_launch(void* const* d_in, const int* in_sizes, int n_in,
                              void* d_out, int out_size, void* d_ws, size_t ws_size,
                              hipStream_t stream) {
    const float* x     = (const float*)d_in[0];
    const int*   ei    = (const int*)d_in[1];
    const float* W_in  = (const float*)d_in[2];
    const float* b_in  = (const float*)d_in[3];
    const float* W_h   = (const float*)d_in[4];
    const float* b_h   = (const float*)d_in[5];
    const float* W_out = (const float*)d_in[6];
    const float* b_out = (const float*)d_in[7];
    float* out = (float*)d_out;

    const int* srcv = ei;
    const int* dstv = ei + NE;

    char* ws = (char*)d_ws;
    _Float16* h0f  = (_Float16*)ws;                              // NN*32 f16
    _Float16* hs0  = h0f + (size_t)NN * 32;                      // NN*32 f16
    _Float16* hs1  = hs0 + (size_t)NN * 32;                      // NN*32 f16
    float* dinv    = (float*)(hs1 + (size_t)NN * 32);            // NN
    _Float16* Wf_in  = (_Float16*)(dinv + NN);                   // 256*256
    _Float16* Wf_h   = Wf_in + 256 * 256;                        // 256*256
    _Float16* Wf_out = Wf_h + 256 * 256;                         // 256*32
    int* histT = (int*)(Wf_out + 256 * 32);                      // NBUCK*NCHK
    int* cntb  = histT + (size_t)NBUCK * NCHK;                   // NBUCKP
    int* data  = cntb + NBUCKP;                                  // NBUCKP*CAP
    int* col   = data + (size_t)NBUCKP * CAP;                    // NBUCKP*CAP
    int* begp  = col + (size_t)NBUCKP * CAP;                     // NN
    int* endp  = begp + NN;                                      // NN

    // --- [bucket count | W fragments] ---
    k_count_wfrag<<<NCHK + WFRAG_BLKS, 512, 0, stream>>>(dstv, histT,
                                                         W_in, W_h, W_out,
                                                         Wf_in, Wf_h, Wf_out);
    // --- per-bucket scan ---
    k_scanb<<<NBUCK, 256, 0, stream>>>(histT, cntb);

    // --- part scatter ---
    k_part<<<NCHK, 512, 0, stream>>>(srcv, dstv, histT, data);

    // --- per-bucket counting sort -> CSR + dinv ---
    k_sortb<<<NBUCK, 256, 0, stream>>>(data, cntb, col, begp, endp, dinv);

    // --- fused MLP (x -> h0f, hs0); after sortb (reads dinv) ---
    k_mlp<<<NT64, 512, 0, stream>>>(x, Wf_in, Wf_h, Wf_out, b_in, b_h, b_out,
                                    dinv, h0f, hs0);

    // --- APPNP: K = 2 (wave-per-node, 16-wide gather) ---
    k_appnp<false><<<(NN + 3) / 4, 256, 0, stream>>>(begp, endp, col, dinv, hs0, h0f, hs1);
    k_appnp<true ><<<(NN + 3) / 4, 256, 0, stream>>>(begp, endp, col, dinv, hs1, h0f, out);
}

// Round 21
// 155.023 us; speedup vs baseline: 1.1111x; 1.1012x over previous
//
#include <hip/hip_runtime.h>

#define NN 100000
#define NE 1600000
#define NT64 1563    // ceil(NN / 64)
#define SCALE_BLKS 1563  // ceil(NN*4 / 256)

#define BSH 7
#define BNODES 128               // nodes per bucket
#define NBUCK 782                // ceil(NN / 128)
#define NBUCKP 784
#define CAP 2560                 // words per bucket region (exp 2048, +11 sigma)
#define ECH 8192                 // edges per chunk
#define NCHK 196                 // ceil(NE / ECH)
#define WFRAG_BLKS 272           // 139264 / 512

typedef _Float16 half8v __attribute__((ext_vector_type(8)));
typedef _Float16 half4v __attribute__((ext_vector_type(4)));
typedef float f32x4 __attribute__((ext_vector_type(4)));

// ---------------- W -> fp16 B-fragment layout ----------------
// Wf[((kt*(N/16)+nt)*64 + l)*8 + j] = W[(kt*32 + (l>>4)*8 + j)*N + nt*16 + (l&15)]

__device__ __forceinline__ void wfrag_one(const float* __restrict__ W,
                                          _Float16* __restrict__ Wf, int idx, int N) {
    int j = idx & 7;
    int l = (idx >> 3) & 63;
    int f = idx >> 9;
    int nt = f % (N / 16);
    int kt = f / (N / 16);
    int k = kt * 32 + (l >> 4) * 8 + j;
    int c = nt * 16 + (l & 15);
    Wf[idx] = (_Float16)W[k * N + c];
}

// ---------------- merged: bucket count (blocks 0..195) | wfrag (196..467) ----------------

__global__ __launch_bounds__(512) void k_count_wfrag(const int* __restrict__ dst,
                                                     int* __restrict__ histT,
                                                     const float* __restrict__ W1,
                                                     const float* __restrict__ W2,
                                                     const float* __restrict__ W3,
                                                     _Float16* __restrict__ Wf1,
                                                     _Float16* __restrict__ Wf2,
                                                     _Float16* __restrict__ Wf3) {
    const int t = threadIdx.x;
    if (blockIdx.x >= NCHK) {
        int idx = (blockIdx.x - NCHK) * 512 + t;
        if (idx < 65536) wfrag_one(W1, Wf1, idx, 256);
        else if (idx < 131072) wfrag_one(W2, Wf2, idx - 65536, 256);
        else if (idx < 139264) wfrag_one(W3, Wf3, idx - 131072, 32);
        return;
    }
    __shared__ int h[NBUCKP];
    const int blk = blockIdx.x;
    for (int b = t; b < NBUCKP; b += 512) h[b] = 0;
    __syncthreads();
    const int ebase = blk * ECH + t * 16;
#pragma unroll
    for (int q = 0; q < 4; q++) {
        int e = ebase + q * 4;
        if (e + 4 <= NE) {
            int4 d4 = *reinterpret_cast<const int4*>(dst + e);
            atomicAdd(&h[d4.x >> BSH], 1);
            atomicAdd(&h[d4.y >> BSH], 1);
            atomicAdd(&h[d4.z >> BSH], 1);
            atomicAdd(&h[d4.w >> BSH], 1);
        } else {
            for (int p = e; p < NE; p++) atomicAdd(&h[dst[p] >> BSH], 1);
            break;
        }
    }
    __syncthreads();
    for (int b = t; b < NBUCK; b += 512) histT[(long long)b * NCHK + blk] = h[b];
}

// ---------------- per-bucket exclusive scan over chunks ----------------

__global__ __launch_bounds__(256) void k_scanb(int* __restrict__ histT,
                                               int* __restrict__ cntb) {
    __shared__ int s[256];
    const int b = blockIdx.x, t = threadIdx.x;
    int* row = histT + (long long)b * NCHK;
    int v = (t < NCHK) ? row[t] : 0;
    s[t] = v;
    __syncthreads();
    for (int off = 1; off < 256; off <<= 1) {
        int u = (t >= off) ? s[t - off] : 0;
        __syncthreads();
        s[t] += u;
        __syncthreads();
    }
    if (t < NCHK) row[t] = s[t] - v;
    if (t == 255) cntb[b] = s[255];
}

// ---------------- merged: part scatter (0..195) | fused MLP (196..1758) ----------------
// MLP emits h0f ONLY (no dinv dependency) -> can overlap the partition scatter.

__global__ __launch_bounds__(512) void k_part_mlp(const int* __restrict__ src,
                                                  const int* __restrict__ dst,
                                                  const int* __restrict__ histT,
                                                  int* __restrict__ data,
                                                  const float* __restrict__ x,
                                                  const _Float16* __restrict__ Wf1,
                                                  const _Float16* __restrict__ Wf2,
                                                  const _Float16* __restrict__ Wf3,
                                                  const float* __restrict__ b1,
                                                  const float* __restrict__ b2,
                                                  const float* __restrict__ b3,
                                                  _Float16* __restrict__ h0f) {
    __shared__ char smem[32768];
    const int t = threadIdx.x;

    if (blockIdx.x < NCHK) {
        // ---- bucket partition scatter ----
        int* curs = (int*)smem;
        const int blk = blockIdx.x;
        for (int b = t; b < NBUCKP; b += 512)
            curs[b] = b * CAP + ((b < NBUCK) ? histT[(long long)b * NCHK + blk] : 0);
        __syncthreads();
        const int ebase = blk * ECH + t * 16;
#pragma unroll
        for (int q = 0; q < 4; q++) {
            int e = ebase + q * 4;
            if (e + 4 <= NE) {
                int4 d4 = *reinterpret_cast<const int4*>(dst + e);
                int4 s4 = *reinterpret_cast<const int4*>(src + e);
                int p0 = atomicAdd(&curs[d4.x >> BSH], 1);
                data[p0] = (s4.x << BSH) | (d4.x & (BNODES - 1));
                int p1 = atomicAdd(&curs[d4.y >> BSH], 1);
                data[p1] = (s4.y << BSH) | (d4.y & (BNODES - 1));
                int p2 = atomicAdd(&curs[d4.z >> BSH], 1);
                data[p2] = (s4.z << BSH) | (d4.z & (BNODES - 1));
                int p3 = atomicAdd(&curs[d4.w >> BSH], 1);
                data[p3] = (s4.w << BSH) | (d4.w & (BNODES - 1));
            } else {
                for (int p = e; p < NE; p++) {
                    int d = dst[p], sv = src[p];
                    int pos = atomicAdd(&curs[d >> BSH], 1);
                    data[pos] = (sv << BSH) | (d & (BNODES - 1));
                }
                break;
            }
        }
        return;
    }

    // ---- fused MLP: 64 rows/block, single 32KB buffer ----
    char* buf = smem;
    const int lane = t & 63;
    const int G = lane >> 4;
    const int w = t >> 6;
    const int T = blockIdx.x - NCHK;
    const long long row0 = (long long)T * 64;

    const half8v* W1f = reinterpret_cast<const half8v*>(Wf1);
    const half8v* W2f = reinterpret_cast<const half8v*>(Wf2);
    float bv1[2], bv2[2];
#pragma unroll
    for (int n2 = 0; n2 < 2; n2++) {
        bv1[n2] = b1[w * 32 + n2 * 16 + (lane & 15)];
        bv2[n2] = b2[w * 32 + n2 * 16 + (lane & 15)];
    }

    // stage x tile fp32 -> fp16 swizzled (issue loads first)
    {
        const float4* A4 = reinterpret_cast<const float4*>(x + row0 * 256);
        float4 v[8];
#pragma unroll
        for (int q = 0; q < 8; q++) {
            int i = t + q * 512;
            int r = i >> 6;
            v[q] = make_float4(0.f, 0.f, 0.f, 0.f);
            if (row0 + r < NN) v[q] = A4[i];
        }
        __builtin_amdgcn_sched_barrier(0);
#pragma unroll
        for (int q = 0; q < 8; q++) {
            int i = t + q * 512;
            int r = i >> 6, c4 = i & 63;
            half4v hv;
            hv[0] = (_Float16)v[q].x; hv[1] = (_Float16)v[q].y;
            hv[2] = (_Float16)v[q].z; hv[3] = (_Float16)v[q].w;
            int bo = (r * 512 + c4 * 8) ^ ((r & 7) << 4);
            *reinterpret_cast<half4v*>(buf + bo) = hv;
        }
    }
    __syncthreads();

    f32x4 acc[4][2];

    // GEMM1
#pragma unroll
    for (int mt = 0; mt < 4; mt++)
#pragma unroll
        for (int n2 = 0; n2 < 2; n2++) acc[mt][n2] = (f32x4)0.f;
#pragma unroll
    for (int kt = 0; kt < 8; kt++) {
        half8v a[4], bfr[2];
#pragma unroll
        for (int n2 = 0; n2 < 2; n2++)
            bfr[n2] = W1f[(kt * 16 + 2 * w + n2) * 64 + lane];
#pragma unroll
        for (int mt = 0; mt < 4; mt++) {
            int row = mt * 16 + (lane & 15);
            int bo = (row * 512 + kt * 64 + (G << 4)) ^ ((row & 7) << 4);
            a[mt] = *reinterpret_cast<const half8v*>(buf + bo);
        }
#pragma unroll
        for (int mt = 0; mt < 4; mt++)
#pragma unroll
            for (int n2 = 0; n2 < 2; n2++)
                acc[mt][n2] = __builtin_amdgcn_mfma_f32_16x16x32_f16(a[mt], bfr[n2], acc[mt][n2], 0, 0, 0);
    }
    __syncthreads();

    // h1 = relu(acc + b1) -> LDS in place
#pragma unroll
    for (int mt = 0; mt < 4; mt++)
#pragma unroll
        for (int n2 = 0; n2 < 2; n2++) {
            int colc = w * 32 + n2 * 16 + (lane & 15);
            float bb = bv1[n2];
#pragma unroll
            for (int r = 0; r < 4; r++) {
                int row = mt * 16 + G * 4 + r;
                float v = fmaxf(acc[mt][n2][r] + bb, 0.f);
                int bo = (row * 512 + colc * 2) ^ ((row & 7) << 4);
                *reinterpret_cast<_Float16*>(buf + bo) = (_Float16)v;
            }
        }
    __syncthreads();

    // GEMM2
#pragma unroll
    for (int mt = 0; mt < 4; mt++)
#pragma unroll
        for (int n2 = 0; n2 < 2; n2++) acc[mt][n2] = (f32x4)0.f;
#pragma unroll
    for (int kt = 0; kt < 8; kt++) {
        half8v a[4], bfr[2];
#pragma unroll
        for (int n2 = 0; n2 < 2; n2++)
            bfr[n2] = W2f[(kt * 16 + 2 * w + n2) * 64 + lane];
#pragma unroll
        for (int mt = 0; mt < 4; mt++) {
            int row = mt * 16 + (lane & 15);
            int bo = (row * 512 + kt * 64 + (G << 4)) ^ ((row & 7) << 4);
            a[mt] = *reinterpret_cast<const half8v*>(buf + bo);
        }
#pragma unroll
        for (int mt = 0; mt < 4; mt++)
#pragma unroll
            for (int n2 = 0; n2 < 2; n2++)
                acc[mt][n2] = __builtin_amdgcn_mfma_f32_16x16x32_f16(a[mt], bfr[n2], acc[mt][n2], 0, 0, 0);
    }
    __syncthreads();

    // h2 = relu(acc + b2) -> LDS in place
#pragma unroll
    for (int mt = 0; mt < 4; mt++)
#pragma unroll
        for (int n2 = 0; n2 < 2; n2++) {
            int colc = w * 32 + n2 * 16 + (lane & 15);
            float bb = bv2[n2];
#pragma unroll
            for (int r = 0; r < 4; r++) {
                int row = mt * 16 + G * 4 + r;
                float v = fmaxf(acc[mt][n2][r] + bb, 0.f);
                int bo = (row * 512 + colc * 2) ^ ((row & 7) << 4);
                *reinterpret_cast<_Float16*>(buf + bo) = (_Float16)v;
            }
        }
    __syncthreads();

    // GEMM3: 8 16x16 tiles, one per wave -> h0f only
    {
        const half8v* W3f = reinterpret_cast<const half8v*>(Wf3);
        const int mt3 = w >> 1, ct3 = w & 1;
        const float bb3 = b3[ct3 * 16 + (lane & 15)];
        f32x4 a3 = (f32x4)0.f;
#pragma unroll
        for (int kt = 0; kt < 8; kt++) {
            int row = mt3 * 16 + (lane & 15);
            int bo = (row * 512 + kt * 64 + (G << 4)) ^ ((row & 7) << 4);
            half8v a = *reinterpret_cast<const half8v*>(buf + bo);
            half8v b = W3f[(kt * 2 + ct3) * 64 + lane];
            a3 = __builtin_amdgcn_mfma_f32_16x16x32_f16(a, b, a3, 0, 0, 0);
        }
        int colc = ct3 * 16 + (lane & 15);
#pragma unroll
        for (int r = 0; r < 4; r++) {
            long long row = row0 + mt3 * 16 + G * 4 + r;
            if (row < NN) h0f[row * 32 + colc] = (_Float16)(a3[r] + bb3);
        }
    }
}

// ---------------- per-bucket degree histogram -> dinv ----------------

__global__ __launch_bounds__(256) void k_deg(const int* __restrict__ data,
                                             const int* __restrict__ cntb,
                                             float* __restrict__ dinv) {
    __shared__ int c[BNODES];
    const int b = blockIdx.x, t = threadIdx.x;
    if (t < BNODES) c[t] = 0;
    __syncthreads();
    const int cnt = cntb[b];
    const int* wp = data + b * CAP;
    for (int e = t; e < cnt; e += 256) atomicAdd(&c[wp[e] & (BNODES - 1)], 1);
    __syncthreads();
    int node = (b << BSH) + t;
    if (t < BNODES && node < NN) dinv[node] = rsqrtf((float)(c[t] + 1));
}

// ---------------- merged: sortb (0..781) | hs0 scale (782..2344) ----------------
// sortb no longer writes dinv (k_deg owns it) -> scale can read dinv race-free.

__global__ __launch_bounds__(256) void k_sortb_scale(const int* __restrict__ data,
                                                     const int* __restrict__ cntb,
                                                     int* __restrict__ col,
                                                     int* __restrict__ begp,
                                                     int* __restrict__ endp,
                                                     const float* __restrict__ dinv,
                                                     const _Float16* __restrict__ h0f,
                                                     _Float16* __restrict__ hs0) {
    const int t = threadIdx.x;
    if (blockIdx.x >= NBUCK) {
        // ---- scale: hs0 = f16(dinv * h0f), one half8v per thread ----
        int idx = (blockIdx.x - NBUCK) * 256 + t;
        if (idx < NN * 4) {
            int node = idx >> 2;
            float dd = dinv[node];
            half8v v = *reinterpret_cast<const half8v*>(h0f + (size_t)idx * 8);
            half8v o;
#pragma unroll
            for (int j = 0; j < 8; j++) o[j] = (_Float16)(dd * (float)v[j]);
            *reinterpret_cast<half8v*>(hs0 + (size_t)idx * 8) = o;
        }
        return;
    }
    __shared__ int hist[BNODES];
    __shared__ int scn[BNODES];
    __shared__ int curs[BNODES];
    const int b = blockIdx.x;
    if (t < BNODES) hist[t] = 0;
    __syncthreads();
    const int cnt = cntb[b];
    const int* wp = data + b * CAP;
    for (int e = t; e < cnt; e += 256) atomicAdd(&hist[wp[e] & (BNODES - 1)], 1);
    __syncthreads();
    if (t < BNODES) scn[t] = hist[t];
    __syncthreads();
    for (int off = 1; off < BNODES; off <<= 1) {
        int v = (t < BNODES && t >= off) ? scn[t - off] : 0;
        __syncthreads();
        if (t < BNODES) scn[t] += v;
        __syncthreads();
    }
    if (t < BNODES) {
        int beg = scn[t] - hist[t];
        curs[t] = beg;
        int node = (b << BSH) + t;
        if (node < NN) {
            begp[node] = b * CAP + beg;
            endp[node] = b * CAP + scn[t];
        }
    }
    __syncthreads();
    for (int e = t; e < cnt; e += 256) {
        int w = wp[e];
        int p = atomicAdd(&curs[w & (BNODES - 1)], 1);
        col[b * CAP + p] = w >> BSH;
    }
}

// ---------------- fused APPNP step: one wave per node, 16 edges in flight ----------------

template<bool FINAL>
__global__ __launch_bounds__(256) void k_appnp(const int* __restrict__ begp,
                                               const int* __restrict__ endp,
                                               const int* __restrict__ col,
                                               const float* __restrict__ dinv,
                                               const _Float16* __restrict__ hs,
                                               const _Float16* __restrict__ h0f,
                                               void* __restrict__ outp) {
    int node = blockIdx.x * 4 + (threadIdx.x >> 6);
    if (node >= NN) return;
    const int lane = threadIdx.x & 63;
    const int slot = lane >> 2;
    const int cg = lane & 3;

    const int beg = begp[node];
    const int end = endp[node];
    const float dd = dinv[node];
    const half8v selfv = *reinterpret_cast<const half8v*>(hs + (size_t)node * 32 + cg * 8);
    const half8v h0v = *reinterpret_cast<const half8v*>(h0f + (size_t)node * 32 + cg * 8);

    float acc[8];
#pragma unroll
    for (int j = 0; j < 8; j++) acc[j] = 0.f;

    for (int e = beg + slot; e < end; e += 16) {
        int s = col[e];
        half8v v = *reinterpret_cast<const half8v*>(hs + (size_t)s * 32 + cg * 8);
#pragma unroll
        for (int j = 0; j < 8; j++) acc[j] += (float)v[j];
    }

#pragma unroll
    for (int off = 4; off < 64; off <<= 1) {
#pragma unroll
        for (int j = 0; j < 8; j++) acc[j] += __shfl_xor(acc[j], off, 64);
    }

    if (slot == 0) {
        float o[8];
#pragma unroll
        for (int j = 0; j < 8; j++)
            o[j] = 0.9f * dd * (acc[j] + (float)selfv[j]) + 0.1f * (float)h0v[j];
        size_t off = (size_t)node * 32 + cg * 8;
        if (FINAL) {
            float4 v0 = make_float4(o[0], o[1], o[2], o[3]);
            float4 v1 = make_float4(o[4], o[5], o[6], o[7]);
            float4* op = reinterpret_cast<float4*>((float*)outp + off);
            op[0] = v0; op[1] = v1;
        } else {
            half8v hv;
#pragma unroll
            for (int j = 0; j < 8; j++) hv[j] = (_Float16)(dd * o[j]);
            *reinterpret_cast<half8v*>((_Float16*)outp + off) = hv;
        }
    }
}

// ---------------- launch ----------------

extern "C" void kernel_launch(void* const* d_in, const int* in_sizes, int n_in,
                              void* d_out, int out_size, void* d_ws, size_t ws_size,
                              hipStream_t stream) {
    const float* x     = (const float*)d_in[0];
    const int*   ei    = (const int*)d_in[1];
    const float* W_in  = (const float*)d_in[2];
    const float* b_in  = (const float*)d_in[3];
    const float* W_h   = (const float*)d_in[4];
    const float* b_h   = (const float*)d_in[5];
    const float* W_out = (const float*)d_in[6];
    const float* b_out = (const float*)d_in[7];
    float* out = (float*)d_out;

    const int* srcv = ei;
    const int* dstv = ei + NE;

    char* ws = (char*)d_ws;
    _Float16* h0f  = (_Float16*)ws;                              // NN*32 f16
    _Float16* hs0  = h0f + (size_t)NN * 32;                      // NN*32 f16
    _Float16* hs1  = hs0 + (size_t)NN * 32;                      // NN*32 f16
    float* dinv    = (float*)(hs1 + (size_t)NN * 32);            // NN
    _Float16* Wf_in  = (_Float16*)(dinv + NN);                   // 256*256
    _Float16* Wf_h   = Wf_in + 256 * 256;                        // 256*256
    _Float16* Wf_out = Wf_h + 256 * 256;                         // 256*32
    int* histT = (int*)(Wf_out + 256 * 32);                      // NBUCK*NCHK
    int* cntb  = histT + (size_t)NBUCK * NCHK;                   // NBUCKP
    int* data  = cntb + NBUCKP;                                  // NBUCKP*CAP
    int* col   = data + (size_t)NBUCKP * CAP;                    // NBUCKP*CAP
    int* begp  = col + (size_t)NBUCKP * CAP;                     // NN
    int* endp  = begp + NN;                                      // NN

    // --- [bucket count | W fragments] ---
    k_count_wfrag<<<NCHK + WFRAG_BLKS, 512, 0, stream>>>(dstv, histT,
                                                         W_in, W_h, W_out,
                                                         Wf_in, Wf_h, Wf_out);
    // --- per-bucket scan ---
    k_scanb<<<NBUCK, 256, 0, stream>>>(histT, cntb);

    // --- [part scatter | fused MLP (h0f only)] ---
    k_part_mlp<<<NCHK + NT64, 512, 0, stream>>>(srcv, dstv, histT, data,
                                                x, Wf_in, Wf_h, Wf_out,
                                                b_in, b_h, b_out, h0f);

    // --- per-bucket degrees -> dinv ---
    k_deg<<<NBUCK, 256, 0, stream>>>(data, cntb, dinv);

    // --- [bucket counting sort | hs0 = dinv*h0f] ---
    k_sortb_scale<<<NBUCK + SCALE_BLKS, 256, 0, stream>>>(data, cntb, col, begp, endp,
                                                          dinv, h0f, hs0);

    // --- APPNP: K = 2 (wave-per-node, 16-wide gather) ---
    k_appnp<false><<<(NN + 3) / 4, 256, 0, stream>>>(begp, endp, col, dinv, hs0, h0f, hs1);
    k_appnp<true ><<<(NN + 3) / 4, 256, 0, stream>>>(begp, endp, col, dinv, hs1, h0f, out);
}

// Round 22
// 154.866 us; speedup vs baseline: 1.1122x; 1.0010x over previous
//
#include <hip/hip_runtime.h>

#define NN 100000
#define NE 1600000
#define NT64 1563    // ceil(NN / 64)
#define SCALE_BLKS 1563  // ceil(NN*4 / 256)

#define BSH 7
#define BNODES 128               // nodes per bucket
#define NBUCK 782                // ceil(NN / 128)
#define NBUCKP 784
#define CAP 2560                 // words per bucket region (exp 2048, +11 sigma)
#define ECH 8192                 // edges per chunk
#define NCHK 196                 // ceil(NE / ECH)
#define WFRAG_BLKS 272           // 139264 / 512

typedef _Float16 half8v __attribute__((ext_vector_type(8)));
typedef _Float16 half4v __attribute__((ext_vector_type(4)));
typedef float f32x4 __attribute__((ext_vector_type(4)));

// ---------------- W -> fp16 B-fragment layout ----------------
// Wf[((kt*(N/16)+nt)*64 + l)*8 + j] = W[(kt*32 + (l>>4)*8 + j)*N + nt*16 + (l&15)]

__device__ __forceinline__ void wfrag_one(const float* __restrict__ W,
                                          _Float16* __restrict__ Wf, int idx, int N) {
    int j = idx & 7;
    int l = (idx >> 3) & 63;
    int f = idx >> 9;
    int nt = f % (N / 16);
    int kt = f / (N / 16);
    int k = kt * 32 + (l >> 4) * 8 + j;
    int c = nt * 16 + (l & 15);
    Wf[idx] = (_Float16)W[k * N + c];
}

// ---------------- merged: bucket count (blocks 0..195) | wfrag (196..467) ----------------

__global__ __launch_bounds__(512) void k_count_wfrag(const int* __restrict__ dst,
                                                     int* __restrict__ histT,
                                                     const float* __restrict__ W1,
                                                     const float* __restrict__ W2,
                                                     const float* __restrict__ W3,
                                                     _Float16* __restrict__ Wf1,
                                                     _Float16* __restrict__ Wf2,
                                                     _Float16* __restrict__ Wf3) {
    const int t = threadIdx.x;
    if (blockIdx.x >= NCHK) {
        int idx = (blockIdx.x - NCHK) * 512 + t;
        if (idx < 65536) wfrag_one(W1, Wf1, idx, 256);
        else if (idx < 131072) wfrag_one(W2, Wf2, idx - 65536, 256);
        else if (idx < 139264) wfrag_one(W3, Wf3, idx - 131072, 32);
        return;
    }
    __shared__ int h[NBUCKP];
    const int blk = blockIdx.x;
    for (int b = t; b < NBUCKP; b += 512) h[b] = 0;
    __syncthreads();
    const int ebase = blk * ECH + t * 16;
#pragma unroll
    for (int q = 0; q < 4; q++) {
        int e = ebase + q * 4;
        if (e + 4 <= NE) {
            int4 d4 = *reinterpret_cast<const int4*>(dst + e);
            atomicAdd(&h[d4.x >> BSH], 1);
            atomicAdd(&h[d4.y >> BSH], 1);
            atomicAdd(&h[d4.z >> BSH], 1);
            atomicAdd(&h[d4.w >> BSH], 1);
        } else {
            for (int p = e; p < NE; p++) atomicAdd(&h[dst[p] >> BSH], 1);
            break;
        }
    }
    __syncthreads();
    for (int b = t; b < NBUCK; b += 512) histT[(long long)b * NCHK + blk] = h[b];
}

// ---------------- per-bucket exclusive scan over chunks ----------------

__global__ __launch_bounds__(256) void k_scanb(int* __restrict__ histT,
                                               int* __restrict__ cntb) {
    __shared__ int s[256];
    const int b = blockIdx.x, t = threadIdx.x;
    int* row = histT + (long long)b * NCHK;
    int v = (t < NCHK) ? row[t] : 0;
    s[t] = v;
    __syncthreads();
    for (int off = 1; off < 256; off <<= 1) {
        int u = (t >= off) ? s[t - off] : 0;
        __syncthreads();
        s[t] += u;
        __syncthreads();
    }
    if (t < NCHK) row[t] = s[t] - v;
    if (t == 255) cntb[b] = s[255];
}

// ---------------- merged: part scatter (0..195) | fused MLP (196..1758) ----------------
// MLP emits h0f ONLY (no dinv dependency) -> can overlap the partition scatter.

__global__ __launch_bounds__(512) void k_part_mlp(const int* __restrict__ src,
                                                  const int* __restrict__ dst,
                                                  const int* __restrict__ histT,
                                                  int* __restrict__ data,
                                                  const float* __restrict__ x,
                                                  const _Float16* __restrict__ Wf1,
                                                  const _Float16* __restrict__ Wf2,
                                                  const _Float16* __restrict__ Wf3,
                                                  const float* __restrict__ b1,
                                                  const float* __restrict__ b2,
                                                  const float* __restrict__ b3,
                                                  _Float16* __restrict__ h0f) {
    __shared__ char smem[32768];
    const int t = threadIdx.x;

    if (blockIdx.x < NCHK) {
        // ---- bucket partition scatter ----
        int* curs = (int*)smem;
        const int blk = blockIdx.x;
        for (int b = t; b < NBUCKP; b += 512)
            curs[b] = b * CAP + ((b < NBUCK) ? histT[(long long)b * NCHK + blk] : 0);
        __syncthreads();
        const int ebase = blk * ECH + t * 16;
#pragma unroll
        for (int q = 0; q < 4; q++) {
            int e = ebase + q * 4;
            if (e + 4 <= NE) {
                int4 d4 = *reinterpret_cast<const int4*>(dst + e);
                int4 s4 = *reinterpret_cast<const int4*>(src + e);
                int p0 = atomicAdd(&curs[d4.x >> BSH], 1);
                data[p0] = (s4.x << BSH) | (d4.x & (BNODES - 1));
                int p1 = atomicAdd(&curs[d4.y >> BSH], 1);
                data[p1] = (s4.y << BSH) | (d4.y & (BNODES - 1));
                int p2 = atomicAdd(&curs[d4.z >> BSH], 1);
                data[p2] = (s4.z << BSH) | (d4.z & (BNODES - 1));
                int p3 = atomicAdd(&curs[d4.w >> BSH], 1);
                data[p3] = (s4.w << BSH) | (d4.w & (BNODES - 1));
            } else {
                for (int p = e; p < NE; p++) {
                    int d = dst[p], sv = src[p];
                    int pos = atomicAdd(&curs[d >> BSH], 1);
                    data[pos] = (sv << BSH) | (d & (BNODES - 1));
                }
                break;
            }
        }
        return;
    }

    // ---- fused MLP: 64 rows/block, single 32KB buffer ----
    char* buf = smem;
    const int lane = t & 63;
    const int G = lane >> 4;
    const int w = t >> 6;
    const int T = blockIdx.x - NCHK;
    const long long row0 = (long long)T * 64;

    const half8v* W1f = reinterpret_cast<const half8v*>(Wf1);
    const half8v* W2f = reinterpret_cast<const half8v*>(Wf2);
    float bv1[2], bv2[2];
#pragma unroll
    for (int n2 = 0; n2 < 2; n2++) {
        bv1[n2] = b1[w * 32 + n2 * 16 + (lane & 15)];
        bv2[n2] = b2[w * 32 + n2 * 16 + (lane & 15)];
    }

    // stage x tile fp32 -> fp16 swizzled (issue loads first)
    {
        const float4* A4 = reinterpret_cast<const float4*>(x + row0 * 256);
        float4 v[8];
#pragma unroll
        for (int q = 0; q < 8; q++) {
            int i = t + q * 512;
            int r = i >> 6;
            v[q] = make_float4(0.f, 0.f, 0.f, 0.f);
            if (row0 + r < NN) v[q] = A4[i];
        }
        __builtin_amdgcn_sched_barrier(0);
#pragma unroll
        for (int q = 0; q < 8; q++) {
            int i = t + q * 512;
            int r = i >> 6, c4 = i & 63;
            half4v hv;
            hv[0] = (_Float16)v[q].x; hv[1] = (_Float16)v[q].y;
            hv[2] = (_Float16)v[q].z; hv[3] = (_Float16)v[q].w;
            int bo = (r * 512 + c4 * 8) ^ ((r & 7) << 4);
            *reinterpret_cast<half4v*>(buf + bo) = hv;
        }
    }
    __syncthreads();

    f32x4 acc[4][2];

    // GEMM1
#pragma unroll
    for (int mt = 0; mt < 4; mt++)
#pragma unroll
        for (int n2 = 0; n2 < 2; n2++) acc[mt][n2] = (f32x4)0.f;
#pragma unroll
    for (int kt = 0; kt < 8; kt++) {
        half8v a[4], bfr[2];
#pragma unroll
        for (int n2 = 0; n2 < 2; n2++)
            bfr[n2] = W1f[(kt * 16 + 2 * w + n2) * 64 + lane];
#pragma unroll
        for (int mt = 0; mt < 4; mt++) {
            int row = mt * 16 + (lane & 15);
            int bo = (row * 512 + kt * 64 + (G << 4)) ^ ((row & 7) << 4);
            a[mt] = *reinterpret_cast<const half8v*>(buf + bo);
        }
#pragma unroll
        for (int mt = 0; mt < 4; mt++)
#pragma unroll
            for (int n2 = 0; n2 < 2; n2++)
                acc[mt][n2] = __builtin_amdgcn_mfma_f32_16x16x32_f16(a[mt], bfr[n2], acc[mt][n2], 0, 0, 0);
    }
    __syncthreads();

    // h1 = relu(acc + b1) -> LDS in place
#pragma unroll
    for (int mt = 0; mt < 4; mt++)
#pragma unroll
        for (int n2 = 0; n2 < 2; n2++) {
            int colc = w * 32 + n2 * 16 + (lane & 15);
            float bb = bv1[n2];
#pragma unroll
            for (int r = 0; r < 4; r++) {
                int row = mt * 16 + G * 4 + r;
                float v = fmaxf(acc[mt][n2][r] + bb, 0.f);
                int bo = (row * 512 + colc * 2) ^ ((row & 7) << 4);
                *reinterpret_cast<_Float16*>(buf + bo) = (_Float16)v;
            }
        }
    __syncthreads();

    // GEMM2
#pragma unroll
    for (int mt = 0; mt < 4; mt++)
#pragma unroll
        for (int n2 = 0; n2 < 2; n2++) acc[mt][n2] = (f32x4)0.f;
#pragma unroll
    for (int kt = 0; kt < 8; kt++) {
        half8v a[4], bfr[2];
#pragma unroll
        for (int n2 = 0; n2 < 2; n2++)
            bfr[n2] = W2f[(kt * 16 + 2 * w + n2) * 64 + lane];
#pragma unroll
        for (int mt = 0; mt < 4; mt++) {
            int row = mt * 16 + (lane & 15);
            int bo = (row * 512 + kt * 64 + (G << 4)) ^ ((row & 7) << 4);
            a[mt] = *reinterpret_cast<const half8v*>(buf + bo);
        }
#pragma unroll
        for (int mt = 0; mt < 4; mt++)
#pragma unroll
            for (int n2 = 0; n2 < 2; n2++)
                acc[mt][n2] = __builtin_amdgcn_mfma_f32_16x16x32_f16(a[mt], bfr[n2], acc[mt][n2], 0, 0, 0);
    }
    __syncthreads();

    // h2 = relu(acc + b2) -> LDS in place
#pragma unroll
    for (int mt = 0; mt < 4; mt++)
#pragma unroll
        for (int n2 = 0; n2 < 2; n2++) {
            int colc = w * 32 + n2 * 16 + (lane & 15);
            float bb = bv2[n2];
#pragma unroll
            for (int r = 0; r < 4; r++) {
                int row = mt * 16 + G * 4 + r;
                float v = fmaxf(acc[mt][n2][r] + bb, 0.f);
                int bo = (row * 512 + colc * 2) ^ ((row & 7) << 4);
                *reinterpret_cast<_Float16*>(buf + bo) = (_Float16)v;
            }
        }
    __syncthreads();

    // GEMM3: 8 16x16 tiles, one per wave -> h0f only
    {
        const half8v* W3f = reinterpret_cast<const half8v*>(Wf3);
        const int mt3 = w >> 1, ct3 = w & 1;
        const float bb3 = b3[ct3 * 16 + (lane & 15)];
        f32x4 a3 = (f32x4)0.f;
#pragma unroll
        for (int kt = 0; kt < 8; kt++) {
            int row = mt3 * 16 + (lane & 15);
            int bo = (row * 512 + kt * 64 + (G << 4)) ^ ((row & 7) << 4);
            half8v a = *reinterpret_cast<const half8v*>(buf + bo);
            half8v b = W3f[(kt * 2 + ct3) * 64 + lane];
            a3 = __builtin_amdgcn_mfma_f32_16x16x32_f16(a, b, a3, 0, 0, 0);
        }
        int colc = ct3 * 16 + (lane & 15);
#pragma unroll
        for (int r = 0; r < 4; r++) {
            long long row = row0 + mt3 * 16 + G * 4 + r;
            if (row < NN) h0f[row * 32 + colc] = (_Float16)(a3[r] + bb3);
        }
    }
}

// ---------------- per-bucket degree histogram -> dinv ----------------

__global__ __launch_bounds__(256) void k_deg(const int* __restrict__ data,
                                             const int* __restrict__ cntb,
                                             float* __restrict__ dinv) {
    __shared__ int c[BNODES];
    const int b = blockIdx.x, t = threadIdx.x;
    if (t < BNODES) c[t] = 0;
    __syncthreads();
    const int cnt = cntb[b];
    const int* wp = data + b * CAP;
    for (int e = t; e < cnt; e += 256) atomicAdd(&c[wp[e] & (BNODES - 1)], 1);
    __syncthreads();
    int node = (b << BSH) + t;
    if (t < BNODES && node < NN) dinv[node] = rsqrtf((float)(c[t] + 1));
}

// ---------------- merged: sortb (0..781) | hs0 scale (782..2344) ----------------
// sortb no longer writes dinv (k_deg owns it) -> scale can read dinv race-free.

__global__ __launch_bounds__(256) void k_sortb_scale(const int* __restrict__ data,
                                                     const int* __restrict__ cntb,
                                                     int* __restrict__ col,
                                                     int* __restrict__ begp,
                                                     int* __restrict__ endp,
                                                     const float* __restrict__ dinv,
                                                     const _Float16* __restrict__ h0f,
                                                     _Float16* __restrict__ hs0) {
    const int t = threadIdx.x;
    if (blockIdx.x >= NBUCK) {
        // ---- scale: hs0 = f16(dinv * h0f), one half8v per thread ----
        int idx = (blockIdx.x - NBUCK) * 256 + t;
        if (idx < NN * 4) {
            int node = idx >> 2;
            float dd = dinv[node];
            half8v v = *reinterpret_cast<const half8v*>(h0f + (size_t)idx * 8);
            half8v o;
#pragma unroll
            for (int j = 0; j < 8; j++) o[j] = (_Float16)(dd * (float)v[j]);
            *reinterpret_cast<half8v*>(hs0 + (size_t)idx * 8) = o;
        }
        return;
    }
    __shared__ int hist[BNODES];
    __shared__ int scn[BNODES];
    __shared__ int curs[BNODES];
    const int b = blockIdx.x;
    if (t < BNODES) hist[t] = 0;
    __syncthreads();
    const int cnt = cntb[b];
    const int* wp = data + b * CAP;
    for (int e = t; e < cnt; e += 256) atomicAdd(&hist[wp[e] & (BNODES - 1)], 1);
    __syncthreads();
    if (t < BNODES) scn[t] = hist[t];
    __syncthreads();
    for (int off = 1; off < BNODES; off <<= 1) {
        int v = (t < BNODES && t >= off) ? scn[t - off] : 0;
        __syncthreads();
        if (t < BNODES) scn[t] += v;
        __syncthreads();
    }
    if (t < BNODES) {
        int beg = scn[t] - hist[t];
        curs[t] = beg;
        int node = (b << BSH) + t;
        if (node < NN) {
            begp[node] = b * CAP + beg;
            endp[node] = b * CAP + scn[t];
        }
    }
    __syncthreads();
    for (int e = t; e < cnt; e += 256) {
        int w = wp[e];
        int p = atomicAdd(&curs[w & (BNODES - 1)], 1);
        col[b * CAP + p] = w >> BSH;
    }
}

// ---------------- fused APPNP step: one wave per node, 16 edges in flight ----------------

template<bool FINAL>
__global__ __launch_bounds__(256) void k_appnp(const int* __restrict__ begp,
                                               const int* __restrict__ endp,
                                               const int* __restrict__ col,
                                               const float* __restrict__ dinv,
                                               const _Float16* __restrict__ hs,
                                               const _Float16* __restrict__ h0f,
                                               void* __restrict__ outp) {
    int node = blockIdx.x * 4 + (threadIdx.x >> 6);
    if (node >= NN) return;
    const int lane = threadIdx.x & 63;
    const int slot = lane >> 2;
    const int cg = lane & 3;

    const int beg = begp[node];
    const int end = endp[node];
    const float dd = dinv[node];
    const half8v selfv = *reinterpret_cast<const half8v*>(hs + (size_t)node * 32 + cg * 8);
    const half8v h0v = *reinterpret_cast<const half8v*>(h0f + (size_t)node * 32 + cg * 8);

    float acc[8];
#pragma unroll
    for (int j = 0; j < 8; j++) acc[j] = 0.f;

    for (int e = beg + slot; e < end; e += 16) {
        int s = col[e];
        half8v v = *reinterpret_cast<const half8v*>(hs + (size_t)s * 32 + cg * 8);
#pragma unroll
        for (int j = 0; j < 8; j++) acc[j] += (float)v[j];
    }

#pragma unroll
    for (int off = 4; off < 64; off <<= 1) {
#pragma unroll
        for (int j = 0; j < 8; j++) acc[j] += __shfl_xor(acc[j], off, 64);
    }

    if (slot == 0) {
        float o[8];
#pragma unroll
        for (int j = 0; j < 8; j++)
            o[j] = 0.9f * dd * (acc[j] + (float)selfv[j]) + 0.1f * (float)h0v[j];
        size_t off = (size_t)node * 32 + cg * 8;
        if (FINAL) {
            float4 v0 = make_float4(o[0], o[1], o[2], o[3]);
            float4 v1 = make_float4(o[4], o[5], o[6], o[7]);
            float4* op = reinterpret_cast<float4*>((float*)outp + off);
            op[0] = v0; op[1] = v1;
        } else {
            half8v hv;
#pragma unroll
            for (int j = 0; j < 8; j++) hv[j] = (_Float16)(dd * o[j]);
            *reinterpret_cast<half8v*>((_Float16*)outp + off) = hv;
        }
    }
}

// ---------------- launch ----------------

extern "C" void kernel_launch(void* const* d_in, const int* in_sizes, int n_in,
                              void* d_out, int out_size, void* d_ws, size_t ws_size,
                              hipStream_t stream) {
    const float* x     = (const float*)d_in[0];
    const int*   ei    = (const int*)d_in[1];
    const float* W_in  = (const float*)d_in[2];
    const float* b_in  = (const float*)d_in[3];
    const float* W_h   = (const float*)d_in[4];
    const float* b_h   = (const float*)d_in[5];
    const float* W_out = (const float*)d_in[6];
    const float* b_out = (const float*)d_in[7];
    float* out = (float*)d_out;

    const int* srcv = ei;
    const int* dstv = ei + NE;

    char* ws = (char*)d_ws;
    _Float16* h0f  = (_Float16*)ws;                              // NN*32 f16
    _Float16* hs0  = h0f + (size_t)NN * 32;                      // NN*32 f16
    _Float16* hs1  = hs0 + (size_t)NN * 32;                      // NN*32 f16
    float* dinv    = (float*)(hs1 + (size_t)NN * 32);            // NN
    _Float16* Wf_in  = (_Float16*)(dinv + NN);                   // 256*256
    _Float16* Wf_h   = Wf_in + 256 * 256;                        // 256*256
    _Float16* Wf_out = Wf_h + 256 * 256;                         // 256*32
    int* histT = (int*)(Wf_out + 256 * 32);                      // NBUCK*NCHK
    int* cntb  = histT + (size_t)NBUCK * NCHK;                   // NBUCKP
    int* data  = cntb + NBUCKP;                                  // NBUCKP*CAP
    int* col   = data + (size_t)NBUCKP * CAP;                    // NBUCKP*CAP
    int* begp  = col + (size_t)NBUCKP * CAP;                     // NN
    int* endp  = begp + NN;                                      // NN

    // --- [bucket count | W fragments] ---
    k_count_wfrag<<<NCHK + WFRAG_BLKS, 512, 0, stream>>>(dstv, histT,
                                                         W_in, W_h, W_out,
                                                         Wf_in, Wf_h, Wf_out);
    // --- per-bucket scan ---
    k_scanb<<<NBUCK, 256, 0, stream>>>(histT, cntb);

    // --- [part scatter | fused MLP (h0f only)] ---
    k_part_mlp<<<NCHK + NT64, 512, 0, stream>>>(srcv, dstv, histT, data,
                                                x, Wf_in, Wf_h, Wf_out,
                                                b_in, b_h, b_out, h0f);

    // --- per-bucket degrees -> dinv ---
    k_deg<<<NBUCK, 256, 0, stream>>>(data, cntb, dinv);

    // --- [bucket counting sort | hs0 = dinv*h0f] ---
    k_sortb_scale<<<NBUCK + SCALE_BLKS, 256, 0, stream>>>(data, cntb, col, begp, endp,
                                                          dinv, h0f, hs0);

    // --- APPNP: K = 2 (wave-per-node, 16-wide gather) ---
    k_appnp<false><<<(NN + 3) / 4, 256, 0, stream>>>(begp, endp, col, dinv, hs0, h0f, hs1);
    k_appnp<true ><<<(NN + 3) / 4, 256, 0, stream>>>(begp, endp, col, dinv, hs1, h0f, out);
}